// Round 8
// baseline (418.871 us; speedup 1.0000x reference)
//
#include <hip/hip_runtime.h>
#include <hip/hip_bf16.h>
#include <math.h>

#define BATCH 2
#define C 192
#define H 128
#define W 256
#define HEADS 6
#define HD 32
#define HW (H * W)      // 32768
#define C3 (3 * C)      // 576
#define NPX (BATCH * HW)  // 65536

typedef unsigned short ushort_t;
using bf16x8 = __attribute__((ext_vector_type(8))) short;
using f32x4  = __attribute__((ext_vector_type(4))) float;

static __device__ __forceinline__ float bfbits2f(ushort_t u) {
    return __uint_as_float(((unsigned)u) << 16);
}
static __device__ __forceinline__ ushort_t f2bfbits(float f) {
    __hip_bfloat16 h = __float2bfloat16(f);
    return *reinterpret_cast<ushort_t*>(&h);
}

// ---------------------------------------------------------------------------
// prep_w: fp32 -> bf16 weights; q-rows of w_qkv pre-scaled by 32^-0.5*log2(e).
// Layout: w_qkv rows 0..575 | w_gate rows 576..767 | w_pre | w_out.
// ---------------------------------------------------------------------------
__global__ __launch_bounds__(256) void prep_w_kernel(
    const float* __restrict__ wq, const float* __restrict__ wg,
    const float* __restrict__ wp, const float* __restrict__ wo,
    ushort_t* __restrict__ dst)
{
    const int i = blockIdx.x * 256 + threadIdx.x;   // float4 index, < 55296
    const float* src; int off, base;
    if (i < 27648)      { src = wq; off = i;         base = 0; }
    else if (i < 36864) { src = wg; off = i - 27648; base = 110592; }
    else if (i < 46080) { src = wp; off = i - 36864; base = 147456; }
    else                { src = wo; off = i - 46080; base = 184320; }
    float4 v = ((const float4*)src)[off];
    if (i < 9216) {   // w_qkv rows 0..191 (the q projection)
        const float sc = 0.25503488f;   // 32^-0.5 * log2(e)
        v.x *= sc; v.y *= sc; v.z *= sc; v.w *= sc;
    }
    ushort4 o;
    o.x = f2bfbits(v.x); o.y = f2bfbits(v.y);
    o.z = f2bfbits(v.z); o.w = f2bfbits(v.w);
    *(ushort4*)(dst + base + off * 4) = o;
}

// ---------------------------------------------------------------------------
// transpose_x: x [B][192][HW] f32 -> x_t [B*HW][192] bf16 (pixel-major).
// ---------------------------------------------------------------------------
__global__ __launch_bounds__(256) void transpose_x_kernel(
    const float* __restrict__ x, ushort_t* __restrict__ xt)
{
    __shared__ uint Xs[64 * 97];   // 24.8 KB
    const int p0 = blockIdx.x * 64;
    const int b  = p0 >> 15, hw0 = p0 & (HW - 1);
    const int t  = threadIdx.x;

    {
        const int px = t & 63, g = t >> 6;
        const float* xb = x + (size_t)b * C * HW + hw0 + px;
#pragma unroll
        for (int i = 0; i < 24; ++i) {
            const int cp = g + i * 4;   // channel pair 0..95
            const float v0 = xb[(size_t)(2 * cp) * HW];
            const float v1 = xb[(size_t)(2 * cp + 1) * HW];
            Xs[px * 97 + cp] = (uint)f2bfbits(v0) | ((uint)f2bfbits(v1) << 16);
        }
    }
    __syncthreads();
    {
        const int px = t >> 2, grp = t & 3;
        uint* dst = (uint*)(xt + (size_t)(p0 + px) * C) + grp * 24;
        const uint* s = &Xs[px * 97 + grp * 24];
#pragma unroll
        for (int i = 0; i < 6; ++i) {
            uint4 u;
            u.x = s[i * 4 + 0]; u.y = s[i * 4 + 1];
            u.z = s[i * 4 + 2]; u.w = s[i * 4 + 3];
            *(uint4*)(dst + i * 4) = u;
        }
    }
}

// ---------------------------------------------------------------------------
// MFMA conv1x1 GEMM (R4 form — best measured, 52.4 us). Block: 4 waves;
// tile M=64 x N=256, K=192; LDS-coalesced px-major stores via [256][72].
// MODE 3 (only instantiation): fused qkv+gate, MT=12: m 0..8 -> buf_t
// [px][576]; m 9..11 -> silu -> gate [px][192]. Chunk map xcd = px/8192.
// ---------------------------------------------------------------------------
template <int MODE, int OUTKIND, int MT>
__global__ __launch_bounds__(256, 2) void conv_mfma_kernel(
    const ushort_t* __restrict__ in_t, const ushort_t* __restrict__ w_bf,
    void* __restrict__ outp, ushort_t* __restrict__ gate, int ostride)
{
    const int lin = blockIdx.x;
    const int xcd = lin & 7;
    const int jj  = lin >> 3;
    const int pin = jj / MT;            // 0..31
    const int m   = jj - pin * MT;      // 0..MT-1
    const int m0  = m * 64;
    const int p0  = (xcd * 32 + pin) * 256;

    const int t  = threadIdx.x;
    const int wv = t >> 6, lane = t & 63, quad = lane >> 4, l16 = lane & 15;

    // As 64x200 (25.6KB) / Ls 256x72 (36.9KB) share this by lifetime.
    __shared__ ushort_t smem[18432];
    ushort_t* As = smem;

    // ---- issue the wave's B panel (24x 16B gathers) ----
    const ushort_t* bp = in_t + (size_t)(p0 + wv * 64 + l16) * C + quad * 8;
    bf16x8 bF[6][4];
#pragma unroll
    for (int ks = 0; ks < 6; ++ks)
#pragma unroll
        for (int ct = 0; ct < 4; ++ct)
            bF[ks][ct] = *(const bf16x8*)(bp + (size_t)(ct * 16) * C + ks * 32);

    // ---- stage A (weights m0..m0+63 x 192) into LDS, padded to 200 ----
    {
        const int row = t >> 2, cg = (t & 3) * 48;
        const ushort_t* src = w_bf + (size_t)(m0 + row) * C + cg;
        ushort_t* dst = &As[row * 200 + cg];
#pragma unroll
        for (int i = 0; i < 6; ++i)
            *(bf16x8*)(dst + i * 8) = *(const bf16x8*)(src + i * 8);
    }
    __syncthreads();

    f32x4 acc[4][4];
#pragma unroll
    for (int rt = 0; rt < 4; ++rt)
#pragma unroll
        for (int ct = 0; ct < 4; ++ct) acc[rt][ct] = f32x4{0.f, 0.f, 0.f, 0.f};

    // ---- MFMA loop ----
#pragma unroll
    for (int ks = 0; ks < 6; ++ks) {
        bf16x8 aF[4];
#pragma unroll
        for (int rt = 0; rt < 4; ++rt)
            aF[rt] = *(const bf16x8*)&As[(rt * 16 + l16) * 200 + quad * 8 + ks * 32];
#pragma unroll
        for (int rt = 0; rt < 4; ++rt)
#pragma unroll
            for (int ct = 0; ct < 4; ++ct)
                acc[rt][ct] = __builtin_amdgcn_mfma_f32_16x16x32_bf16(
                    aF[rt], bF[ks][ct], acc[rt][ct], 0, 0, 0);
    }

    // ---- per-lane epilogue transforms ----
    const bool isg = (MODE == 3) && (m >= 9);   // gate block of fused kernel
    if (MODE == 1 || isg) {
#pragma unroll
        for (int rt = 0; rt < 4; ++rt)
#pragma unroll
            for (int ct = 0; ct < 4; ++ct) {
                f32x4 v = acc[rt][ct];
#pragma unroll
                for (int r = 0; r < 4; ++r)
                    v[r] = v[r] / (1.f + __expf(-v[r]));
                acc[rt][ct] = v;
            }
    }

    if constexpr (OUTKIND == 0) {
        // ---- LDS-transposed coalesced store ----
        __syncthreads();                 // all As reads complete
        ushort_t* Ls = smem;             // [256][72]
#pragma unroll
        for (int rt = 0; rt < 4; ++rt)
#pragma unroll
            for (int ct = 0; ct < 4; ++ct) {
                const f32x4 v = acc[rt][ct];
                ushort4 o;
                o.x = f2bfbits(v[0]); o.y = f2bfbits(v[1]);
                o.z = f2bfbits(v[2]); o.w = f2bfbits(v[3]);
                *(ushort4*)&Ls[(wv * 64 + ct * 16 + l16) * 72 +
                               rt * 16 + quad * 4] = o;
            }
        __syncthreads();

        ushort_t* ob; int osr, chb;
        if constexpr (MODE == 3) {
            ob  = isg ? gate : (ushort_t*)outp;
            osr = isg ? C : C3;
            chb = isg ? m0 - C3 : m0;
        } else {
            ob = (ushort_t*)outp; osr = ostride; chb = m0;
        }
        const int pxl = t >> 3, c8 = (t & 7) * 8;
#pragma unroll
        for (int r = 0; r < 8; ++r) {
            const int px = r * 32 + pxl;
            const bf16x8 v = *(const bf16x8*)&Ls[px * 72 + c8];
            *(bf16x8*)(ob + (size_t)(p0 + px) * osr + chb + c8) = v;
        }
    } else {
        const int bb = p0 >> 15;
        const int hwb = (p0 & (HW - 1)) + wv * 64;
        float* ob = (float*)outp + ((size_t)bb * C + m0) * HW + hwb;
#pragma unroll
        for (int rt = 0; rt < 4; ++rt)
#pragma unroll
            for (int ct = 0; ct < 4; ++ct) {
                const f32x4 v = acc[rt][ct];
#pragma unroll
                for (int r = 0; r < 4; ++r)
                    ob[(size_t)(rt * 16 + quad * 4 + r) * HW + ct * 16 + l16] = v[r];
            }
    }
}

// ---------------------------------------------------------------------------
// attention_dw: depthwise-3x3 FUSED into attention. Eliminates the dwconv
// kernel and the 150 MB buf_qkv roundtrip. Each block (b, y, head) applies
// the 3x3 depthwise conv to buf_t rows y-1..y+1 for its 96 head-channels
// (px = t, x-halo from L1-overlapping loads), staging q -> Qs, k -> Ks,
// v -> Vt (transposed) in LDS; then the proven swapped-QK^T base-2-softmax
// attention runs from LDS. Qs becomes Pb after aQ frags are read (R0 trick).
// LDS 63360 B -> 2 blocks/CU. Heads of one row grid-adjacent (head = j%6)
// for row-halo L2 reuse; chunk decode matches conv1's px/8192 map.
// ---------------------------------------------------------------------------
__global__ __launch_bounds__(256, 2) void attention_dw_kernel(
    const ushort_t* __restrict__ tin, const float* __restrict__ wd,
    const float* __restrict__ rpb, ushort_t* __restrict__ att)
{
    const int lin  = blockIdx.x;        // 0..1535
    const int xcd  = lin & 7;
    const int j    = lin >> 3;          // 0..191
    const int b    = xcd >> 2;
    const int yl   = j / 6;
    const int head = j - yl * 6;
    const int y    = (xcd & 3) * 32 + yl;
    const int t    = threadIdx.x;
    const int wv   = t >> 6;
    const int lane = t & 63;
    const int quad = lane >> 4;
    const int l16  = lane & 15;

    __shared__ __align__(16) char smem[63360];
    ushort_t* Ks  = (ushort_t*)smem;                // [256][40] = 20480
    ushort_t* Qs  = (ushort_t*)(smem + 20480);      // [256][40] -> Pb
    ushort_t* Vt  = (ushort_t*)(smem + 40960);      // [32][264] = 16896
    ushort_t* rb  = (ushort_t*)(smem + 57856);      // [2][512]  =  2048
    float*    wdl = (float*)(smem + 59904);         // [3][32][9]=  3456
    float*    Ol  = (float*)smem;                   // [32][257] overlay

    // depthwise weights for this head's 96 channels -> LDS
    if (t < 216) {
        const int s = t / 72, i = t - s * 72;
        *(float4*)&wdl[s * 288 + i * 4] =
            *(const float4*)(wd + (size_t)(s * 192 + head * HD) * 9 + i * 4);
    }
    // base-2 rpb table (2 shift copies)
    {
        const float LOG2E = 1.4426950408889634f;
#pragma unroll
        for (int s2 = 0; s2 < 2; ++s2)
#pragma unroll
            for (int pp = 0; pp < 2; ++pp) {
                const int k = pp * 256 + t;
                const int src = k + s2;
                rb[s2 * 512 + k] =
                    f2bfbits(src <= 510 ? rpb[src * HEADS + head] * LOG2E : 0.f);
            }
    }
    __syncthreads();

    // ---- depthwise 3x3: thread t owns px x = t of row y ----
    {
        const ushort_t* base = tin +
            ((size_t)(b * HW + y * W) + t) * C3 + head * HD;
#pragma unroll
        for (int s = 0; s < 3; ++s) {
#pragma unroll
            for (int c8 = 0; c8 < 4; ++c8) {
                float acc[8];
#pragma unroll
                for (int k = 0; k < 8; ++k) acc[k] = 0.f;
#pragma unroll
                for (int dy = -1; dy <= 1; ++dy) {
                    const int yy = y + dy;
                    if (yy < 0 || yy >= H) continue;
                    const ushort_t* rp =
                        base + (ptrdiff_t)dy * (W * C3) + s * C + c8 * 8;
#pragma unroll
                    for (int dx = -1; dx <= 1; ++dx) {
                        const int xx = t + dx;
                        if (xx < 0 || xx >= W) continue;
                        const bf16x8 v = *(const bf16x8*)(rp + (ptrdiff_t)dx * C3);
                        const float* wk =
                            &wdl[(s * 32 + c8 * 8) * 9 + (dy + 1) * 3 + (dx + 1)];
#pragma unroll
                        for (int k = 0; k < 8; ++k)
                            acc[k] += bfbits2f((ushort_t)v[k]) * wk[k * 9];
                    }
                }
                if (s < 2) {
                    bf16x8 o;
#pragma unroll
                    for (int k = 0; k < 8; ++k) o[k] = (short)f2bfbits(acc[k]);
                    ushort_t* dst = (s == 0) ? Qs : Ks;
                    *(bf16x8*)&dst[t * 40 + c8 * 8] = o;
                } else {
#pragma unroll
                    for (int k = 0; k < 8; ++k)
                        Vt[(c8 * 8 + k) * 264 + t] = f2bfbits(acc[k]);
                }
            }
        }
    }
    __syncthreads();

    // Q fragments from LDS, then Qs becomes the P buffer
    bf16x8 aQ[4];
#pragma unroll
    for (int rt = 0; rt < 4; ++rt)
        aQ[rt] = *(const bf16x8*)&Qs[(wv * 64 + rt * 16 + l16) * 40 + quad * 8];
    __syncthreads();
    ushort_t* PbW = Qs + wv * 2560;

    float lsum[4] = {0.f, 0.f, 0.f, 0.f};
    f32x4 o_acc[4][2];
#pragma unroll
    for (int rt = 0; rt < 4; ++rt)
#pragma unroll
        for (int ct = 0; ct < 2; ++ct)
            o_acc[rt][ct] = f32x4{0.f, 0.f, 0.f, 0.f};

    const int ibase = wv * 64 + l16 + 255 - quad * 4;

    for (int c2 = 0; c2 < 8; ++c2) {
#pragma unroll
        for (int half = 0; half < 2; ++half) {
            const int n = c2 * 2 + half;
            const bf16x8 bK = *(const bf16x8*)&Ks[(n * 16 + l16) * 40 + quad * 8];
#pragma unroll
            for (int rt = 0; rt < 4; ++rt) {
                // bias^T: idx = i - j + 255 = (ibase + rt*16 - n*16) - reg
                const int a  = ibase + rt * 16 - n * 16 - 3;  // 0..507
                const int s2 = a & 1;
                const uint* tp = (const uint*)(rb + s2 * 512 + (a - s2));
                const uint u0 = tp[0], u1 = tp[1];  // rpb2[a..a+3]
                f32x4 s;
                s[0] = __uint_as_float(u1 & 0xffff0000u);
                s[1] = __uint_as_float(u1 << 16);
                s[2] = __uint_as_float(u0 & 0xffff0000u);
                s[3] = __uint_as_float(u0 << 16);
                s = __builtin_amdgcn_mfma_f32_16x16x32_bf16(bK, aQ[rt], s, 0, 0, 0);
                const float p0 = __builtin_amdgcn_exp2f(s[0]);
                const float p1 = __builtin_amdgcn_exp2f(s[1]);
                const float p2 = __builtin_amdgcn_exp2f(s[2]);
                const float p3 = __builtin_amdgcn_exp2f(s[3]);
                lsum[rt] += (p0 + p1) + (p2 + p3);
                uint2 dd;
                dd.x = (uint)f2bfbits(p0) | ((uint)f2bfbits(p1) << 16);
                dd.y = (uint)f2bfbits(p2) | ((uint)f2bfbits(p3) << 16);
                *(uint2*)&PbW[(rt * 16 + l16) * 40 + half * 16 + quad * 4] = dd;
            }
        }
        // PV for this 32-wide j block
#pragma unroll
        for (int rt = 0; rt < 4; ++rt) {
            const bf16x8 aP = *(const bf16x8*)&PbW[(rt * 16 + l16) * 40 + quad * 8];
#pragma unroll
            for (int ct = 0; ct < 2; ++ct) {
                const bf16x8 bV = *(const bf16x8*)
                    &Vt[(ct * 16 + l16) * 264 + c2 * 32 + quad * 8];
                o_acc[rt][ct] = __builtin_amdgcn_mfma_f32_16x16x32_bf16(
                    aP, bV, o_acc[rt][ct], 0, 0, 0);
            }
        }
    }

    // softmax denominators: lane-local partial + reduce across quads
    float linv[4];
#pragma unroll
    for (int rt = 0; rt < 4; ++rt) {
        float v = lsum[rt];
        v += __shfl_xor(v, 16);
        v += __shfl_xor(v, 32);
        linv[rt] = 1.f / v;
    }

    __syncthreads();   // all waves done with Ks/Pb/Vt -> overlay Ol
#pragma unroll
    for (int rt = 0; rt < 4; ++rt) {
        const int i = wv * 64 + rt * 16 + quad * 4;
        float sc[4];
#pragma unroll
        for (int reg = 0; reg < 4; ++reg)
            sc[reg] = __shfl(linv[rt], quad * 4 + reg);
#pragma unroll
        for (int ct = 0; ct < 2; ++ct) {
            const int c = ct * 16 + l16;
#pragma unroll
            for (int reg = 0; reg < 4; ++reg)
                Ol[c * 257 + i + reg] = o_acc[rt][ct][reg] * sc[reg];
        }
    }
    __syncthreads();

    // coalesced store: 4 lanes per px row (64B contiguous per px)
    const size_t orow = (size_t)b * HW + (size_t)y * W;
    const int pxl = t >> 2, part = t & 3;
#pragma unroll
    for (int r = 0; r < 4; ++r) {
        const int px = r * 64 + pxl;
        bf16x8 o;
#pragma unroll
        for (int k = 0; k < 8; ++k)
            o[k] = (short)f2bfbits(Ol[(part * 8 + k) * 257 + px]);
        *(bf16x8*)(att + (orow + px) * C + head * HD + part * 8) = o;
    }
}

// ---------------------------------------------------------------------------
// conv2_fused: out = ((att @ w_pre) * gate) @ w_out, f32 ch-major.
// B panel (att rows) loaded once for all ms blocks; A panels in 12-load
// halves; Zw stride 204 (bank-conflict-free phase-2 ds_read_b128).
// ---------------------------------------------------------------------------
__global__ __launch_bounds__(256, 3) void conv2_fused_kernel(
    const ushort_t* __restrict__ att_t, const ushort_t* __restrict__ gatep,
    const ushort_t* __restrict__ wpre, const ushort_t* __restrict__ wout,
    float* __restrict__ outp)
{
    const int lin = blockIdx.x;          // 0..511
    const int xcd = lin & 7;
    const int pin = lin >> 3;            // 0..63
    const int p0  = (xcd * 64 + pin) * 128;

    const int t  = threadIdx.x;
    const int wv = t >> 6, lane = t & 63, quad = lane >> 4, l16 = lane & 15;

    __shared__ ushort_t Zs[4][32 * 204];   // 52.2 KB, per-wave scratch
    ushort_t* Zw = Zs[wv];
    const int pxw = p0 + wv * 32;

    // ---- B panel (att rows) loaded ONCE for all 3 ms blocks ----
    const ushort_t* bp = att_t + (size_t)(pxw + l16) * C + quad * 8;
    bf16x8 bB[6][2];
#pragma unroll
    for (int ks = 0; ks < 6; ++ks) {
        bB[ks][0] = *(const bf16x8*)(bp + ks * 32);
        bB[ks][1] = *(const bf16x8*)(bp + (size_t)16 * C + ks * 32);
    }

    // ---------- phase 1: z = (att @ w_pre) * gate ----------
#pragma unroll
    for (int ms = 0; ms < 3; ++ms) {
        f32x4 acc[4][2];
#pragma unroll
        for (int rt = 0; rt < 4; ++rt)
#pragma unroll
            for (int ct = 0; ct < 2; ++ct) acc[rt][ct] = f32x4{0.f,0.f,0.f,0.f};

        const ushort_t* ap = wpre + (size_t)(ms * 64 + l16) * C + quad * 8;
#pragma unroll
        for (int h = 0; h < 2; ++h) {
            bf16x8 aF[3][4];
#pragma unroll
            for (int k2 = 0; k2 < 3; ++k2)
#pragma unroll
                for (int rt = 0; rt < 4; ++rt)
                    aF[k2][rt] = *(const bf16x8*)(ap + (size_t)(rt * 16) * C +
                                                  (h * 3 + k2) * 32);
#pragma unroll
            for (int k2 = 0; k2 < 3; ++k2)
#pragma unroll
                for (int rt = 0; rt < 4; ++rt) {
                    acc[rt][0] = __builtin_amdgcn_mfma_f32_16x16x32_bf16(
                        aF[k2][rt], bB[h * 3 + k2][0], acc[rt][0], 0, 0, 0);
                    acc[rt][1] = __builtin_amdgcn_mfma_f32_16x16x32_bf16(
                        aF[k2][rt], bB[h * 3 + k2][1], acc[rt][1], 0, 0, 0);
                }
        }

        // gate multiply + z -> per-wave LDS
#pragma unroll
        for (int rt = 0; rt < 4; ++rt)
#pragma unroll
            for (int ct = 0; ct < 2; ++ct) {
                const int px = pxw + ct * 16 + l16;
                const int ch = ms * 64 + rt * 16 + quad * 4;
                const ushort4 g = *(const ushort4*)(gatep + (size_t)px * C + ch);
                f32x4 v = acc[rt][ct];
                v[0] *= bfbits2f(g.x); v[1] *= bfbits2f(g.y);
                v[2] *= bfbits2f(g.z); v[3] *= bfbits2f(g.w);
                ushort4 o;
                o.x = f2bfbits(v[0]); o.y = f2bfbits(v[1]);
                o.z = f2bfbits(v[2]); o.w = f2bfbits(v[3]);
                *(ushort4*)&Zw[(ct * 16 + l16) * 204 + ch] = o;
            }
    }

    // ---------- phase 2: out = z @ w_out (f32 ch-major, non-temporal) ------
    const int bb  = p0 >> 15;
    const int hwb = (p0 & (HW - 1)) + wv * 32;
#pragma unroll
    for (int ms = 0; ms < 3; ++ms) {
        f32x4 acc[4][2];
#pragma unroll
        for (int rt = 0; rt < 4; ++rt)
#pragma unroll
            for (int ct = 0; ct < 2; ++ct) acc[rt][ct] = f32x4{0.f,0.f,0.f,0.f};

        const ushort_t* ap = wout + (size_t)(ms * 64 + l16) * C + quad * 8;
#pragma unroll
        for (int h = 0; h < 2; ++h) {
            bf16x8 aF[3][4];
#pragma unroll
            for (int k2 = 0; k2 < 3; ++k2)
#pragma unroll
                for (int rt = 0; rt < 4; ++rt)
                    aF[k2][rt] = *(const bf16x8*)(ap + (size_t)(rt * 16) * C +
                                                  (h * 3 + k2) * 32);
#pragma unroll
            for (int k2 = 0; k2 < 3; ++k2) {
                const int ks = h * 3 + k2;
                const bf16x8 b0 = *(const bf16x8*)&Zw[l16 * 204 + quad * 8 + ks * 32];
                const bf16x8 b1 = *(const bf16x8*)&Zw[(16 + l16) * 204 + quad * 8 + ks * 32];
#pragma unroll
                for (int rt = 0; rt < 4; ++rt) {
                    acc[rt][0] = __builtin_amdgcn_mfma_f32_16x16x32_bf16(
                        aF[k2][rt], b0, acc[rt][0], 0, 0, 0);
                    acc[rt][1] = __builtin_amdgcn_mfma_f32_16x16x32_bf16(
                        aF[k2][rt], b1, acc[rt][1], 0, 0, 0);
                }
            }
        }
        float* ob = outp + ((size_t)bb * C + ms * 64) * HW + hwb;
#pragma unroll
        for (int rt = 0; rt < 4; ++rt)
#pragma unroll
            for (int ct = 0; ct < 2; ++ct) {
                const f32x4 v = acc[rt][ct];
#pragma unroll
                for (int r = 0; r < 4; ++r)
                    __builtin_nontemporal_store(v[r],
                        &ob[(size_t)(rt * 16 + quad * 4 + r) * HW + ct * 16 + l16]);
            }
    }
}

// ---------------------------------------------------------------------------
extern "C" void kernel_launch(void* const* d_in, const int* in_sizes, int n_in,
                              void* d_out, int out_size, void* d_ws, size_t ws_size,
                              hipStream_t stream)
{
    const float* x       = (const float*)d_in[0];
    const float* rpb     = (const float*)d_in[1];
    const float* w_qkv   = (const float*)d_in[2];
    const float* w_depth = (const float*)d_in[3];
    const float* w_pre   = (const float*)d_in[4];
    const float* w_out   = (const float*)d_in[5];
    const float* w_gate  = (const float*)d_in[6];
    float* out = (float*)d_out;

    // workspace layout, aliased by lifetime:
    //   wbf 0..368640 | gate_t 524288..25690112 | buf_t 25690112..101187584 |
    //   x_t / att_t 101187584..126353408 (x_t dead after conv1)
    char* wsb = (char*)d_ws;
    ushort_t* wbf      = (ushort_t*)wsb;           // qkv|gate|pre|out rows
    ushort_t* w_pre_b  = wbf + 147456;
    ushort_t* w_out_b  = wbf + 184320;
    ushort_t* gate_t   = (ushort_t*)(wsb + 524288u);
    ushort_t* buf_t    = (ushort_t*)(wsb + 25690112u);
    ushort_t* x_t      = (ushort_t*)(wsb + 101187584u);
    ushort_t* att_t    = (ushort_t*)(wsb + 101187584u);

    dim3 blk(256);

    prep_w_kernel<<<dim3(216), blk, 0, stream>>>(w_qkv, w_gate, w_pre, w_out, wbf);
    transpose_x_kernel<<<dim3(NPX / 64), blk, 0, stream>>>(x, x_t);
    // buf_t = x_t @ w_qkv (q pre-scaled), gate_t = silu(x_t @ w_gate)
    conv_mfma_kernel<3, 0, 12><<<dim3(3072), blk, 0, stream>>>(
        x_t, wbf, buf_t, gate_t, C3);
    // att_t = attention(dwconv3x3(buf_t), rpb)   px-major bf16
    attention_dw_kernel<<<dim3(H * HEADS * BATCH), blk, 0, stream>>>(
        buf_t, w_depth, rpb, att_t);
    // out = ((att_t @ w_pre) * gate_t) @ w_out   (fused, f32 ch-major)
    conv2_fused_kernel<<<dim3(NPX / 128), blk, 0, stream>>>(
        att_t, gate_t, w_pre_b, w_out_b, out);
}

// Round 9
// 331.588 us; speedup vs baseline: 1.2632x; 1.2632x over previous
//
#include <hip/hip_runtime.h>
#include <hip/hip_bf16.h>
#include <math.h>

#define BATCH 2
#define C 192
#define H 128
#define W 256
#define HEADS 6
#define HD 32
#define HW (H * W)      // 32768
#define C3 (3 * C)      // 576
#define NPX (BATCH * HW)  // 65536

typedef unsigned short ushort_t;
using bf16x8 = __attribute__((ext_vector_type(8))) short;
using f32x4  = __attribute__((ext_vector_type(4))) float;

static __device__ __forceinline__ float bfbits2f(ushort_t u) {
    return __uint_as_float(((unsigned)u) << 16);
}
static __device__ __forceinline__ ushort_t f2bfbits(float f) {
    __hip_bfloat16 h = __float2bfloat16(f);
    return *reinterpret_cast<ushort_t*>(&h);
}

// ---------------------------------------------------------------------------
// prep_w: fp32 -> bf16 weights; q-rows of w_qkv pre-scaled by 32^-0.5*log2(e).
// Layout: w_qkv rows 0..575 | w_gate rows 576..767 | w_pre | w_out.
// ---------------------------------------------------------------------------
__global__ __launch_bounds__(256) void prep_w_kernel(
    const float* __restrict__ wq, const float* __restrict__ wg,
    const float* __restrict__ wp, const float* __restrict__ wo,
    ushort_t* __restrict__ dst)
{
    const int i = blockIdx.x * 256 + threadIdx.x;   // float4 index, < 55296
    const float* src; int off, base;
    if (i < 27648)      { src = wq; off = i;         base = 0; }
    else if (i < 36864) { src = wg; off = i - 27648; base = 110592; }
    else if (i < 46080) { src = wp; off = i - 36864; base = 147456; }
    else                { src = wo; off = i - 46080; base = 184320; }
    float4 v = ((const float4*)src)[off];
    if (i < 9216) {   // w_qkv rows 0..191 (the q projection)
        const float sc = 0.25503488f;   // 32^-0.5 * log2(e)
        v.x *= sc; v.y *= sc; v.z *= sc; v.w *= sc;
    }
    ushort4 o;
    o.x = f2bfbits(v.x); o.y = f2bfbits(v.y);
    o.z = f2bfbits(v.z); o.w = f2bfbits(v.w);
    *(ushort4*)(dst + base + off * 4) = o;
}

// ---------------------------------------------------------------------------
// transpose_x: x [B][192][HW] f32 -> x_t [B*HW][192] bf16 (pixel-major).
// ---------------------------------------------------------------------------
__global__ __launch_bounds__(256) void transpose_x_kernel(
    const float* __restrict__ x, ushort_t* __restrict__ xt)
{
    __shared__ uint Xs[64 * 97];   // 24.8 KB
    const int p0 = blockIdx.x * 64;
    const int b  = p0 >> 15, hw0 = p0 & (HW - 1);
    const int t  = threadIdx.x;

    {
        const int px = t & 63, g = t >> 6;
        const float* xb = x + (size_t)b * C * HW + hw0 + px;
#pragma unroll
        for (int i = 0; i < 24; ++i) {
            const int cp = g + i * 4;   // channel pair 0..95
            const float v0 = xb[(size_t)(2 * cp) * HW];
            const float v1 = xb[(size_t)(2 * cp + 1) * HW];
            Xs[px * 97 + cp] = (uint)f2bfbits(v0) | ((uint)f2bfbits(v1) << 16);
        }
    }
    __syncthreads();
    {
        const int px = t >> 2, grp = t & 3;
        uint* dst = (uint*)(xt + (size_t)(p0 + px) * C) + grp * 24;
        const uint* s = &Xs[px * 97 + grp * 24];
#pragma unroll
        for (int i = 0; i < 6; ++i) {
            uint4 u;
            u.x = s[i * 4 + 0]; u.y = s[i * 4 + 1];
            u.z = s[i * 4 + 2]; u.w = s[i * 4 + 3];
            *(uint4*)(dst + i * 4) = u;
        }
    }
}

// ---------------------------------------------------------------------------
// MFMA conv1x1 GEMM (R4 structure, occupancy raised 2->4 blocks/CU).
// Block: 4 waves; tile M=64 x N=256, K=192; LDS-coalesced px-major stores.
// launch_bounds(256,4): VGPR<=128 (measured use 76-84), LDS 36.9KB*4=147KB.
// MODE 3 (only instantiation): fused qkv+gate, MT=12: m 0..8 -> buf_t
// [px][576]; m 9..11 -> silu -> gate [px][192]. Chunk map xcd = px/8192.
// ---------------------------------------------------------------------------
template <int MODE, int OUTKIND, int MT>
__global__ __launch_bounds__(256, 4) void conv_mfma_kernel(
    const ushort_t* __restrict__ in_t, const ushort_t* __restrict__ w_bf,
    void* __restrict__ outp, ushort_t* __restrict__ gate, int ostride)
{
    const int lin = blockIdx.x;
    const int xcd = lin & 7;
    const int jj  = lin >> 3;
    const int pin = jj / MT;            // 0..31
    const int m   = jj - pin * MT;      // 0..MT-1
    const int m0  = m * 64;
    const int p0  = (xcd * 32 + pin) * 256;

    const int t  = threadIdx.x;
    const int wv = t >> 6, lane = t & 63, quad = lane >> 4, l16 = lane & 15;

    // As 64x200 (25.6KB) / Ls 256x72 (36.9KB) share this by lifetime.
    __shared__ ushort_t smem[18432];
    ushort_t* As = smem;

    // ---- issue the wave's B panel (24x 16B gathers) ----
    const ushort_t* bp = in_t + (size_t)(p0 + wv * 64 + l16) * C + quad * 8;
    bf16x8 bF[6][4];
#pragma unroll
    for (int ks = 0; ks < 6; ++ks)
#pragma unroll
        for (int ct = 0; ct < 4; ++ct)
            bF[ks][ct] = *(const bf16x8*)(bp + (size_t)(ct * 16) * C + ks * 32);

    // ---- stage A (weights m0..m0+63 x 192) into LDS, padded to 200 ----
    {
        const int row = t >> 2, cg = (t & 3) * 48;
        const ushort_t* src = w_bf + (size_t)(m0 + row) * C + cg;
        ushort_t* dst = &As[row * 200 + cg];
#pragma unroll
        for (int i = 0; i < 6; ++i)
            *(bf16x8*)(dst + i * 8) = *(const bf16x8*)(src + i * 8);
    }
    __syncthreads();

    f32x4 acc[4][4];
#pragma unroll
    for (int rt = 0; rt < 4; ++rt)
#pragma unroll
        for (int ct = 0; ct < 4; ++ct) acc[rt][ct] = f32x4{0.f, 0.f, 0.f, 0.f};

    // ---- MFMA loop ----
#pragma unroll
    for (int ks = 0; ks < 6; ++ks) {
        bf16x8 aF[4];
#pragma unroll
        for (int rt = 0; rt < 4; ++rt)
            aF[rt] = *(const bf16x8*)&As[(rt * 16 + l16) * 200 + quad * 8 + ks * 32];
#pragma unroll
        for (int rt = 0; rt < 4; ++rt)
#pragma unroll
            for (int ct = 0; ct < 4; ++ct)
                acc[rt][ct] = __builtin_amdgcn_mfma_f32_16x16x32_bf16(
                    aF[rt], bF[ks][ct], acc[rt][ct], 0, 0, 0);
    }

    // ---- per-lane epilogue transforms ----
    const bool isg = (MODE == 3) && (m >= 9);   // gate block of fused kernel
    if (MODE == 1 || isg) {
#pragma unroll
        for (int rt = 0; rt < 4; ++rt)
#pragma unroll
            for (int ct = 0; ct < 4; ++ct) {
                f32x4 v = acc[rt][ct];
#pragma unroll
                for (int r = 0; r < 4; ++r)
                    v[r] = v[r] / (1.f + __expf(-v[r]));
                acc[rt][ct] = v;
            }
    }

    if constexpr (OUTKIND == 0) {
        // ---- LDS-transposed coalesced store ----
        __syncthreads();                 // all As reads complete
        ushort_t* Ls = smem;             // [256][72]
#pragma unroll
        for (int rt = 0; rt < 4; ++rt)
#pragma unroll
            for (int ct = 0; ct < 4; ++ct) {
                const f32x4 v = acc[rt][ct];
                ushort4 o;
                o.x = f2bfbits(v[0]); o.y = f2bfbits(v[1]);
                o.z = f2bfbits(v[2]); o.w = f2bfbits(v[3]);
                *(ushort4*)&Ls[(wv * 64 + ct * 16 + l16) * 72 +
                               rt * 16 + quad * 4] = o;
            }
        __syncthreads();

        ushort_t* ob; int osr, chb;
        if constexpr (MODE == 3) {
            ob  = isg ? gate : (ushort_t*)outp;
            osr = isg ? C : C3;
            chb = isg ? m0 - C3 : m0;
        } else {
            ob = (ushort_t*)outp; osr = ostride; chb = m0;
        }
        const int pxl = t >> 3, c8 = (t & 7) * 8;
#pragma unroll
        for (int r = 0; r < 8; ++r) {
            const int px = r * 32 + pxl;
            const bf16x8 v = *(const bf16x8*)&Ls[px * 72 + c8];
            *(bf16x8*)(ob + (size_t)(p0 + px) * osr + chb + c8) = v;
        }
    } else {
        const int bb = p0 >> 15;
        const int hwb = (p0 & (HW - 1)) + wv * 64;
        float* ob = (float*)outp + ((size_t)bb * C + m0) * HW + hwb;
#pragma unroll
        for (int rt = 0; rt < 4; ++rt)
#pragma unroll
            for (int ct = 0; ct < 4; ++ct) {
                const f32x4 v = acc[rt][ct];
#pragma unroll
                for (int r = 0; r < 4; ++r)
                    ob[(size_t)(rt * 16 + quad * 4 + r) * HW + ct * 16 + l16] = v[r];
            }
    }
}

// ---------------------------------------------------------------------------
// depthwise 3x3, pixel-major, LDS-coalesced stores. Chunk swizzle
// xcd = px/8192, reversed within-chunk (reads freshest buf_t first).
// launch_bounds(256,4): cap VGPR at 128 so occupancy reaches 4 blocks/CU.
// ---------------------------------------------------------------------------
__global__ __launch_bounds__(256, 4) void dwconv3x3_px_kernel(
    const ushort_t* __restrict__ tin, const float* __restrict__ wd,
    ushort_t* __restrict__ out)
{
    __shared__ float wloc[576];
    __shared__ ushort_t Ld[128 * 72];   // 18.4 KB
    const int bx = blockIdx.x;                       // 0..511
    const int px_blk = (bx & 7) * 64 + (63 - (bx >> 3));
    const int cb  = blockIdx.y;
    const int tid = threadIdx.x;
    if (tid < 144)
        *(float4*)&wloc[tid * 4] = *(const float4*)(wd + cb * 576 + tid * 4);
    __syncthreads();

    const int chloc = (tid & 7) * 8;
    const int pxl0 = (tid >> 3) * 4;               // local px 0..124
    const int px = px_blk * 128 + pxl0;
    const int x0 = px & (W - 1);
    const int y  = (px >> 8) & (H - 1);

    const ushort_t* tb = tin + (size_t)px * C3 + cb * 64 + chloc;

    float acc[4][8];
#pragma unroll
    for (int i = 0; i < 4; ++i)
#pragma unroll
        for (int k = 0; k < 8; ++k) acc[i][k] = 0.f;

#pragma unroll
    for (int dy = -1; dy <= 1; ++dy) {
        const int yy = y + dy;
        if (yy < 0 || yy >= H) continue;
        const ushort_t* rp = tb + (ptrdiff_t)dy * W * C3;

        float f[6][8];
#pragma unroll
        for (int d = 0; d < 6; ++d) {
            const int xx = x0 + d - 1;
            if (xx < 0 || xx >= W) {
#pragma unroll
                for (int k = 0; k < 8; ++k) f[d][k] = 0.f;
            } else {
                const bf16x8 v = *(const bf16x8*)(rp + (ptrdiff_t)(d - 1) * C3);
#pragma unroll
                for (int k = 0; k < 8; ++k) f[d][k] = bfbits2f((ushort_t)v[k]);
            }
        }
#pragma unroll
        for (int k = 0; k < 8; ++k) {
            const float* wk = &wloc[(chloc + k) * 9 + (dy + 1) * 3];
            const float w0 = wk[0], w1 = wk[1], w2 = wk[2];
#pragma unroll
            for (int i = 0; i < 4; ++i)
                acc[i][k] += f[i][k] * w0 + f[i + 1][k] * w1 + f[i + 2][k] * w2;
        }
    }

    // stage to LDS [128][72]
#pragma unroll
    for (int i = 0; i < 4; ++i) {
        bf16x8 o;
#pragma unroll
        for (int k = 0; k < 8; ++k) o[k] = (short)f2bfbits(acc[i][k]);
        *(bf16x8*)&Ld[(pxl0 + i) * 72 + chloc] = o;
    }
    __syncthreads();

    // coalesced store: 8 lanes per px row (128B contiguous per px)
    const int pxl = tid >> 3, c8 = (tid & 7) * 8;
#pragma unroll
    for (int r = 0; r < 4; ++r) {
        const int p = r * 32 + pxl;
        const bf16x8 v = *(const bf16x8*)&Ld[p * 72 + c8];
        *(bf16x8*)(out + (size_t)(px_blk * 128 + p) * C3 + cb * 64 + c8) = v;
    }
}

// ---------------------------------------------------------------------------
// MFMA attention (R5 form): swapped QK^T, base-2 softmax, no Q/K LDS staging,
// 39424 B LDS -> 4 blocks/CU, 1-D grid with chunk-matched decode.
// ---------------------------------------------------------------------------
__global__ __launch_bounds__(256, 4) void attention_mfma_kernel(
    const ushort_t* __restrict__ qkv, const float* __restrict__ rpb,
    ushort_t* __restrict__ att)
{
    const int lin  = blockIdx.x;        // 0..1535
    const int xcd  = lin & 7;
    const int j    = lin >> 3;          // 0..191
    const int b    = xcd >> 2;
    const int y    = (xcd & 3) * 32 + (j & 31);
    const int head = j >> 5;            // 0..5
    const int t    = threadIdx.x;
    const int wv   = t >> 6;
    const int lane = t & 63;
    const int quad = lane >> 4;
    const int l16  = lane & 15;

    __shared__ __align__(16) char smem[39424];
    ushort_t* Vt = (ushort_t*)smem;               // [32][264]  = 16896 B
    ushort_t* Pb = (ushort_t*)(smem + 16896);     // [4][64][40]= 20480 B
    ushort_t* rb = (ushort_t*)(smem + 37376);     // [2][512]   =  2048 B
    float*    Ol = (float*)smem;                  // [32][257] epilogue overlay

    const size_t rowbase = ((size_t)b * HW + (size_t)y * W) * C3;
    const ushort_t* qbase = qkv + rowbase + head * HD + quad * 8;
    const ushort_t* kbase = qbase + C;

    // ---- stage V transposed into LDS; build base-2 rpb table (2 copies) ----
    {
        const ushort_t* rowp = qkv + rowbase + (size_t)t * C3 + head * HD;
        bf16x8 vfr[4];
#pragma unroll
        for (int g = 0; g < 4; ++g)
            vfr[g] = *(const bf16x8*)(rowp + 2 * C + g * 8);
#pragma unroll
        for (int g = 0; g < 4; ++g)
#pragma unroll
            for (int k = 0; k < 8; ++k)
                Vt[(g * 8 + k) * 264 + t] = (ushort_t)vfr[g][k];
    }
    {
        const float LOG2E = 1.4426950408889634f;
#pragma unroll
        for (int s2 = 0; s2 < 2; ++s2)
#pragma unroll
            for (int pp = 0; pp < 2; ++pp) {
                const int k = pp * 256 + t;
                const int src = k + s2;
                rb[s2 * 512 + k] =
                    f2bfbits(src <= 510 ? rpb[src * HEADS + head] * LOG2E : 0.f);
            }
    }

    // Q fragments (B-operand layout) direct from global; first K fragment.
    bf16x8 aQ[4];
#pragma unroll
    for (int rt = 0; rt < 4; ++rt)
        aQ[rt] = *(const bf16x8*)(qbase + (size_t)(wv * 64 + rt * 16 + l16) * C3);
    bf16x8 bK = *(const bf16x8*)(kbase + (size_t)l16 * C3);

    __syncthreads();

    ushort_t* PbW = Pb + wv * 2560;
    float lsum[4] = {0.f, 0.f, 0.f, 0.f};
    f32x4 o_acc[4][2];
#pragma unroll
    for (int rt = 0; rt < 4; ++rt)
#pragma unroll
        for (int ct = 0; ct < 2; ++ct)
            o_acc[rt][ct] = f32x4{0.f, 0.f, 0.f, 0.f};

    const int ibase = wv * 64 + l16 + 255 - quad * 4;

    for (int c2 = 0; c2 < 8; ++c2) {
#pragma unroll
        for (int half = 0; half < 2; ++half) {
            const int n  = c2 * 2 + half;
            const int nn = (n < 15) ? n + 1 : 15;
            const bf16x8 bKn =
                *(const bf16x8*)(kbase + (size_t)(nn * 16 + l16) * C3);
#pragma unroll
            for (int rt = 0; rt < 4; ++rt) {
                // bias^T: idx = i - j + 255 = (ibase + rt*16 - n*16) - reg
                const int a  = ibase + rt * 16 - n * 16 - 3;  // 0..507
                const int s2 = a & 1;
                const uint* tp = (const uint*)(rb + s2 * 512 + (a - s2));
                const uint u0 = tp[0], u1 = tp[1];  // rpb2[a..a+3]
                f32x4 s;
                s[0] = __uint_as_float(u1 & 0xffff0000u);
                s[1] = __uint_as_float(u1 << 16);
                s[2] = __uint_as_float(u0 & 0xffff0000u);
                s[3] = __uint_as_float(u0 << 16);
                s = __builtin_amdgcn_mfma_f32_16x16x32_bf16(bK, aQ[rt], s, 0, 0, 0);
                const float p0 = __builtin_amdgcn_exp2f(s[0]);
                const float p1 = __builtin_amdgcn_exp2f(s[1]);
                const float p2 = __builtin_amdgcn_exp2f(s[2]);
                const float p3 = __builtin_amdgcn_exp2f(s[3]);
                lsum[rt] += (p0 + p1) + (p2 + p3);
                uint2 dd;
                dd.x = (uint)f2bfbits(p0) | ((uint)f2bfbits(p1) << 16);
                dd.y = (uint)f2bfbits(p2) | ((uint)f2bfbits(p3) << 16);
                *(uint2*)&PbW[(rt * 16 + l16) * 40 + half * 16 + quad * 4] = dd;
            }
            bK = bKn;
        }
        // PV for this 32-wide j block
#pragma unroll
        for (int rt = 0; rt < 4; ++rt) {
            const bf16x8 aP = *(const bf16x8*)&PbW[(rt * 16 + l16) * 40 + quad * 8];
#pragma unroll
            for (int ct = 0; ct < 2; ++ct) {
                const bf16x8 bV = *(const bf16x8*)
                    &Vt[(ct * 16 + l16) * 264 + c2 * 32 + quad * 8];
                o_acc[rt][ct] = __builtin_amdgcn_mfma_f32_16x16x32_bf16(
                    aP, bV, o_acc[rt][ct], 0, 0, 0);
            }
        }
    }

    // softmax denominators: lane-local partial + reduce across quads
    float linv[4];
#pragma unroll
    for (int rt = 0; rt < 4; ++rt) {
        float v = lsum[rt];
        v += __shfl_xor(v, 16);
        v += __shfl_xor(v, 32);
        linv[rt] = 1.f / v;
    }

    __syncthreads();   // all waves done with Vt/Pb -> overlay Ol
#pragma unroll
    for (int rt = 0; rt < 4; ++rt) {
        const int i = wv * 64 + rt * 16 + quad * 4;
        float sc[4];
#pragma unroll
        for (int reg = 0; reg < 4; ++reg)
            sc[reg] = __shfl(linv[rt], quad * 4 + reg);
#pragma unroll
        for (int ct = 0; ct < 2; ++ct) {
            const int c = ct * 16 + l16;
#pragma unroll
            for (int reg = 0; reg < 4; ++reg)
                Ol[c * 257 + i + reg] = o_acc[rt][ct][reg] * sc[reg];
        }
    }
    __syncthreads();

    // coalesced store: 4 lanes per px row (64B contiguous per px)
    const size_t orow = (size_t)b * HW + (size_t)y * W;
    const int pxl = t >> 2, part = t & 3;
#pragma unroll
    for (int r = 0; r < 4; ++r) {
        const int px = r * 64 + pxl;
        bf16x8 o;
#pragma unroll
        for (int k = 0; k < 8; ++k)
            o[k] = (short)f2bfbits(Ol[(part * 8 + k) * 257 + px]);
        *(bf16x8*)(att + (orow + px) * C + head * HD + part * 8) = o;
    }
}

// ---------------------------------------------------------------------------
// conv2_fused v4: out = ((att @ w_pre) * gate) @ w_out, f32 ch-major.
// R5 lesson: grid 512 = hard 2 blocks/CU cap (Occupancy 19%, everything
// latency-exposed). v4: 1024 blocks x 64 px (16 px/wave), Zs 26.1 KB,
// launch_bounds(256,4) -> 4 blocks/CU, doubling waves in flight.
// B panel loaded once per wave (6 loads); A panels in 12-load halves;
// Zw stride 204 (bank-spread phase-2 ds_read_b128). NT f32 stores.
// ---------------------------------------------------------------------------
__global__ __launch_bounds__(256, 4) void conv2_fused_kernel(
    const ushort_t* __restrict__ att_t, const ushort_t* __restrict__ gatep,
    const ushort_t* __restrict__ wpre, const ushort_t* __restrict__ wout,
    float* __restrict__ outp)
{
    const int lin = blockIdx.x;          // 0..1023
    const int xcd = lin & 7;
    const int pin = lin >> 3;            // 0..127
    const int p0  = xcd * 8192 + pin * 64;

    const int t  = threadIdx.x;
    const int wv = t >> 6, lane = t & 63, quad = lane >> 4, l16 = lane & 15;

    __shared__ ushort_t Zs[4][16 * 204];   // 26.1 KB, per-wave scratch
    ushort_t* Zw = Zs[wv];
    const int pxw = p0 + wv * 16;

    // ---- B panel (att rows, 16 px x 192 ch) loaded ONCE ----
    const ushort_t* bp = att_t + (size_t)(pxw + l16) * C + quad * 8;
    bf16x8 bB[6];
#pragma unroll
    for (int ks = 0; ks < 6; ++ks)
        bB[ks] = *(const bf16x8*)(bp + ks * 32);

    // ---------- phase 1: z = (att @ w_pre) * gate ----------
#pragma unroll
    for (int ms = 0; ms < 3; ++ms) {
        f32x4 acc[4];
#pragma unroll
        for (int rt = 0; rt < 4; ++rt) acc[rt] = f32x4{0.f,0.f,0.f,0.f};

        const ushort_t* ap = wpre + (size_t)(ms * 64 + l16) * C + quad * 8;
#pragma unroll
        for (int h = 0; h < 2; ++h) {
            bf16x8 aF[3][4];
#pragma unroll
            for (int k2 = 0; k2 < 3; ++k2)
#pragma unroll
                for (int rt = 0; rt < 4; ++rt)
                    aF[k2][rt] = *(const bf16x8*)(ap + (size_t)(rt * 16) * C +
                                                  (h * 3 + k2) * 32);
#pragma unroll
            for (int k2 = 0; k2 < 3; ++k2)
#pragma unroll
                for (int rt = 0; rt < 4; ++rt)
                    acc[rt] = __builtin_amdgcn_mfma_f32_16x16x32_bf16(
                        aF[k2][rt], bB[h * 3 + k2], acc[rt], 0, 0, 0);
        }

        // gate multiply + z -> per-wave LDS
#pragma unroll
        for (int rt = 0; rt < 4; ++rt) {
            const int px = pxw + l16;
            const int ch = ms * 64 + rt * 16 + quad * 4;
            const ushort4 g = *(const ushort4*)(gatep + (size_t)px * C + ch);
            f32x4 v = acc[rt];
            v[0] *= bfbits2f(g.x); v[1] *= bfbits2f(g.y);
            v[2] *= bfbits2f(g.z); v[3] *= bfbits2f(g.w);
            ushort4 o;
            o.x = f2bfbits(v[0]); o.y = f2bfbits(v[1]);
            o.z = f2bfbits(v[2]); o.w = f2bfbits(v[3]);
            *(ushort4*)&Zw[l16 * 204 + ch] = o;
        }
    }

    // ---------- phase 2: out = z @ w_out (f32 ch-major, non-temporal) ------
    const int bb  = p0 >> 15;
    const int hwb = (p0 & (HW - 1)) + wv * 16;
#pragma unroll
    for (int ms = 0; ms < 3; ++ms) {
        f32x4 acc[4];
#pragma unroll
        for (int rt = 0; rt < 4; ++rt) acc[rt] = f32x4{0.f,0.f,0.f,0.f};

        const ushort_t* ap = wout + (size_t)(ms * 64 + l16) * C + quad * 8;
#pragma unroll
        for (int h = 0; h < 2; ++h) {
            bf16x8 aF[3][4];
#pragma unroll
            for (int k2 = 0; k2 < 3; ++k2)
#pragma unroll
                for (int rt = 0; rt < 4; ++rt)
                    aF[k2][rt] = *(const bf16x8*)(ap + (size_t)(rt * 16) * C +
                                                  (h * 3 + k2) * 32);
#pragma unroll
            for (int k2 = 0; k2 < 3; ++k2) {
                const int ks = h * 3 + k2;
                const bf16x8 b0 = *(const bf16x8*)&Zw[l16 * 204 + quad * 8 + ks * 32];
#pragma unroll
                for (int rt = 0; rt < 4; ++rt)
                    acc[rt] = __builtin_amdgcn_mfma_f32_16x16x32_bf16(
                        aF[k2][rt], b0, acc[rt], 0, 0, 0);
            }
        }
        float* ob = outp + ((size_t)bb * C + ms * 64) * HW + hwb;
#pragma unroll
        for (int rt = 0; rt < 4; ++rt) {
            const f32x4 v = acc[rt];
#pragma unroll
            for (int r = 0; r < 4; ++r)
                __builtin_nontemporal_store(v[r],
                    &ob[(size_t)(rt * 16 + quad * 4 + r) * HW + l16]);
        }
    }
}

// ---------------------------------------------------------------------------
extern "C" void kernel_launch(void* const* d_in, const int* in_sizes, int n_in,
                              void* d_out, int out_size, void* d_ws, size_t ws_size,
                              hipStream_t stream)
{
    const float* x       = (const float*)d_in[0];
    const float* rpb     = (const float*)d_in[1];
    const float* w_qkv   = (const float*)d_in[2];
    const float* w_depth = (const float*)d_in[3];
    const float* w_pre   = (const float*)d_in[4];
    const float* w_out   = (const float*)d_in[5];
    const float* w_gate  = (const float*)d_in[6];
    float* out = (float*)d_out;

    // workspace layout, aliased by lifetime:
    char* wsb = (char*)d_ws;
    ushort_t* wbf      = (ushort_t*)wsb;           // qkv|gate|pre|out rows
    ushort_t* w_pre_b  = wbf + 147456;
    ushort_t* w_out_b  = wbf + 184320;
    ushort_t* gate_t   = (ushort_t*)(wsb + 524288u);
    ushort_t* buf_t    = (ushort_t*)(wsb + 25690112u);
    ushort_t* att_t    = (ushort_t*)(wsb + 25690112u);
    ushort_t* buf_qkv  = (ushort_t*)(wsb + 101187584u);
    ushort_t* x_t      = (ushort_t*)(wsb + 101187584u);

    dim3 blk(256);

    prep_w_kernel<<<dim3(216), blk, 0, stream>>>(w_qkv, w_gate, w_pre, w_out, wbf);
    transpose_x_kernel<<<dim3(NPX / 64), blk, 0, stream>>>(x, x_t);
    // buf_t = x_t @ w_qkv (q pre-scaled), gate_t = silu(x_t @ w_gate)
    conv_mfma_kernel<3, 0, 12><<<dim3(3072), blk, 0, stream>>>(
        x_t, wbf, buf_t, gate_t, C3);
    // qkv = depthwise3x3(t)                   px-major bf16 [px][576]
    dwconv3x3_px_kernel<<<dim3(NPX / 128, 9), blk, 0, stream>>>(
        buf_t, w_depth, buf_qkv);
    // att_t = attention(qkv, rpb)             px-major bf16
    attention_mfma_kernel<<<dim3(H * HEADS * BATCH), blk, 0, stream>>>(
        buf_qkv, rpb, att_t);
    // out = ((att_t @ w_pre) * gate_t) @ w_out   (fused, f32 ch-major)
    conv2_fused_kernel<<<dim3(NPX / 64), blk, 0, stream>>>(
        att_t, gate_t, w_pre_b, w_out_b, out);
}

// Round 10
// 293.420 us; speedup vs baseline: 1.4276x; 1.1301x over previous
//
#include <hip/hip_runtime.h>
#include <hip/hip_bf16.h>
#include <math.h>

#define BATCH 2
#define C 192
#define H 128
#define W 256
#define HEADS 6
#define HD 32
#define HW (H * W)      // 32768
#define C3 (3 * C)      // 576
#define NPX (BATCH * HW)  // 65536

typedef unsigned short ushort_t;
using bf16x8 = __attribute__((ext_vector_type(8))) short;
using f32x4  = __attribute__((ext_vector_type(4))) float;

static __device__ __forceinline__ float bfbits2f(ushort_t u) {
    return __uint_as_float(((unsigned)u) << 16);
}
static __device__ __forceinline__ ushort_t f2bfbits(float f) {
    __hip_bfloat16 h = __float2bfloat16(f);
    return *reinterpret_cast<ushort_t*>(&h);
}

// ---------------------------------------------------------------------------
// prep_w: fp32 -> bf16 weights; q-rows of w_qkv pre-scaled by 32^-0.5*log2(e).
// Layout: w_qkv rows 0..575 | w_gate rows 576..767 | w_pre | w_out.
// ---------------------------------------------------------------------------
__global__ __launch_bounds__(256) void prep_w_kernel(
    const float* __restrict__ wq, const float* __restrict__ wg,
    const float* __restrict__ wp, const float* __restrict__ wo,
    ushort_t* __restrict__ dst)
{
    const int i = blockIdx.x * 256 + threadIdx.x;   // float4 index, < 55296
    const float* src; int off, base;
    if (i < 27648)      { src = wq; off = i;         base = 0; }
    else if (i < 36864) { src = wg; off = i - 27648; base = 110592; }
    else if (i < 46080) { src = wp; off = i - 36864; base = 147456; }
    else                { src = wo; off = i - 46080; base = 184320; }
    float4 v = ((const float4*)src)[off];
    if (i < 9216) {   // w_qkv rows 0..191 (the q projection)
        const float sc = 0.25503488f;   // 32^-0.5 * log2(e)
        v.x *= sc; v.y *= sc; v.z *= sc; v.w *= sc;
    }
    ushort4 o;
    o.x = f2bfbits(v.x); o.y = f2bfbits(v.y);
    o.z = f2bfbits(v.z); o.w = f2bfbits(v.w);
    *(ushort4*)(dst + base + off * 4) = o;
}

// ---------------------------------------------------------------------------
// transpose_x: x [B][192][HW] f32 -> x_t [B*HW][192] bf16 (pixel-major).
// ---------------------------------------------------------------------------
__global__ __launch_bounds__(256) void transpose_x_kernel(
    const float* __restrict__ x, ushort_t* __restrict__ xt)
{
    __shared__ uint Xs[64 * 97];   // 24.8 KB
    const int p0 = blockIdx.x * 64;
    const int b  = p0 >> 15, hw0 = p0 & (HW - 1);
    const int t  = threadIdx.x;

    {
        const int px = t & 63, g = t >> 6;
        const float* xb = x + (size_t)b * C * HW + hw0 + px;
#pragma unroll
        for (int i = 0; i < 24; ++i) {
            const int cp = g + i * 4;   // channel pair 0..95
            const float v0 = xb[(size_t)(2 * cp) * HW];
            const float v1 = xb[(size_t)(2 * cp + 1) * HW];
            Xs[px * 97 + cp] = (uint)f2bfbits(v0) | ((uint)f2bfbits(v1) << 16);
        }
    }
    __syncthreads();
    {
        const int px = t >> 2, grp = t & 3;
        uint* dst = (uint*)(xt + (size_t)(p0 + px) * C) + grp * 24;
        const uint* s = &Xs[px * 97 + grp * 24];
#pragma unroll
        for (int i = 0; i < 6; ++i) {
            uint4 u;
            u.x = s[i * 4 + 0]; u.y = s[i * 4 + 1];
            u.z = s[i * 4 + 2]; u.w = s[i * 4 + 3];
            *(uint4*)(dst + i * 4) = u;
        }
    }
}

// ---------------------------------------------------------------------------
// MFMA conv1x1 GEMM (R4 structure, best measured 52.4 us). Block: 4 waves;
// tile M=64 x N=256, K=192; LDS-coalesced px-major stores. Delta vs R4:
// Ls is a SEPARATE buffer (no As overlay) -> the pre-store barrier goes
// away (one convoy point per block instead of two). 62.5 KB LDS, 2 blk/CU.
// MODE 3 (only instantiation): fused qkv+gate, MT=12: m 0..8 -> buf_t
// [px][576]; m 9..11 -> silu -> gate [px][192]. Chunk map xcd = px/8192.
// ---------------------------------------------------------------------------
template <int MODE, int OUTKIND, int MT>
__global__ __launch_bounds__(256, 2) void conv_mfma_kernel(
    const ushort_t* __restrict__ in_t, const ushort_t* __restrict__ w_bf,
    void* __restrict__ outp, ushort_t* __restrict__ gate, int ostride)
{
    const int lin = blockIdx.x;
    const int xcd = lin & 7;
    const int jj  = lin >> 3;
    const int pin = jj / MT;            // 0..31
    const int m   = jj - pin * MT;      // 0..MT-1
    const int m0  = m * 64;
    const int p0  = (xcd * 32 + pin) * 256;

    const int t  = threadIdx.x;
    const int wv = t >> 6, lane = t & 63, quad = lane >> 4, l16 = lane & 15;

    __shared__ ushort_t As[64 * 200];   // 25.6 KB (padded stride 200)
    __shared__ ushort_t Ls[256 * 72];   // 36.9 KB epilogue transpose tile

    // ---- issue the wave's B panel (24x 16B gathers) ----
    const ushort_t* bp = in_t + (size_t)(p0 + wv * 64 + l16) * C + quad * 8;
    bf16x8 bF[6][4];
#pragma unroll
    for (int ks = 0; ks < 6; ++ks)
#pragma unroll
        for (int ct = 0; ct < 4; ++ct)
            bF[ks][ct] = *(const bf16x8*)(bp + (size_t)(ct * 16) * C + ks * 32);

    // ---- stage A (weights m0..m0+63 x 192) into LDS, padded to 200 ----
    {
        const int row = t >> 2, cg = (t & 3) * 48;
        const ushort_t* src = w_bf + (size_t)(m0 + row) * C + cg;
        ushort_t* dst = &As[row * 200 + cg];
#pragma unroll
        for (int i = 0; i < 6; ++i)
            *(bf16x8*)(dst + i * 8) = *(const bf16x8*)(src + i * 8);
    }
    __syncthreads();

    f32x4 acc[4][4];
#pragma unroll
    for (int rt = 0; rt < 4; ++rt)
#pragma unroll
        for (int ct = 0; ct < 4; ++ct) acc[rt][ct] = f32x4{0.f, 0.f, 0.f, 0.f};

    // ---- MFMA loop ----
#pragma unroll
    for (int ks = 0; ks < 6; ++ks) {
        bf16x8 aF[4];
#pragma unroll
        for (int rt = 0; rt < 4; ++rt)
            aF[rt] = *(const bf16x8*)&As[(rt * 16 + l16) * 200 + quad * 8 + ks * 32];
#pragma unroll
        for (int rt = 0; rt < 4; ++rt)
#pragma unroll
            for (int ct = 0; ct < 4; ++ct)
                acc[rt][ct] = __builtin_amdgcn_mfma_f32_16x16x32_bf16(
                    aF[rt], bF[ks][ct], acc[rt][ct], 0, 0, 0);
    }

    // ---- per-lane epilogue transforms ----
    const bool isg = (MODE == 3) && (m >= 9);   // gate block of fused kernel
    if (MODE == 1 || isg) {
#pragma unroll
        for (int rt = 0; rt < 4; ++rt)
#pragma unroll
            for (int ct = 0; ct < 4; ++ct) {
                f32x4 v = acc[rt][ct];
#pragma unroll
                for (int r = 0; r < 4; ++r)
                    v[r] = v[r] / (1.f + __expf(-v[r]));
                acc[rt][ct] = v;
            }
    }

    if constexpr (OUTKIND == 0) {
        // ---- LDS-transposed coalesced store (single barrier) ----
#pragma unroll
        for (int rt = 0; rt < 4; ++rt)
#pragma unroll
            for (int ct = 0; ct < 4; ++ct) {
                const f32x4 v = acc[rt][ct];
                ushort4 o;
                o.x = f2bfbits(v[0]); o.y = f2bfbits(v[1]);
                o.z = f2bfbits(v[2]); o.w = f2bfbits(v[3]);
                *(ushort4*)&Ls[(wv * 64 + ct * 16 + l16) * 72 +
                               rt * 16 + quad * 4] = o;
            }
        __syncthreads();

        ushort_t* ob; int osr, chb;
        if constexpr (MODE == 3) {
            ob  = isg ? gate : (ushort_t*)outp;
            osr = isg ? C : C3;
            chb = isg ? m0 - C3 : m0;
        } else {
            ob = (ushort_t*)outp; osr = ostride; chb = m0;
        }
        const int pxl = t >> 3, c8 = (t & 7) * 8;
#pragma unroll
        for (int r = 0; r < 8; ++r) {
            const int px = r * 32 + pxl;
            const bf16x8 v = *(const bf16x8*)&Ls[px * 72 + c8];
            *(bf16x8*)(ob + (size_t)(p0 + px) * osr + chb + c8) = v;
        }
    } else {
        const int bb = p0 >> 15;
        const int hwb = (p0 & (HW - 1)) + wv * 64;
        float* ob = (float*)outp + ((size_t)bb * C + m0) * HW + hwb;
#pragma unroll
        for (int rt = 0; rt < 4; ++rt)
#pragma unroll
            for (int ct = 0; ct < 4; ++ct) {
                const f32x4 v = acc[rt][ct];
#pragma unroll
                for (int r = 0; r < 4; ++r)
                    ob[(size_t)(rt * 16 + quad * 4 + r) * HW + ct * 16 + l16] = v[r];
            }
    }
}

// ---------------------------------------------------------------------------
// depthwise 3x3, pixel-major, LDS-coalesced stores (R5 form, uncapped).
// Chunk swizzle xcd = px/8192, reversed within-chunk.
// ---------------------------------------------------------------------------
__global__ __launch_bounds__(256) void dwconv3x3_px_kernel(
    const ushort_t* __restrict__ tin, const float* __restrict__ wd,
    ushort_t* __restrict__ out)
{
    __shared__ float wloc[576];
    __shared__ ushort_t Ld[128 * 72];   // 18.4 KB
    const int bx = blockIdx.x;                       // 0..511
    const int px_blk = (bx & 7) * 64 + (63 - (bx >> 3));
    const int cb  = blockIdx.y;
    const int tid = threadIdx.x;
    if (tid < 144)
        *(float4*)&wloc[tid * 4] = *(const float4*)(wd + cb * 576 + tid * 4);
    __syncthreads();

    const int chloc = (tid & 7) * 8;
    const int pxl0 = (tid >> 3) * 4;               // local px 0..124
    const int px = px_blk * 128 + pxl0;
    const int x0 = px & (W - 1);
    const int y  = (px >> 8) & (H - 1);

    const ushort_t* tb = tin + (size_t)px * C3 + cb * 64 + chloc;

    float acc[4][8];
#pragma unroll
    for (int i = 0; i < 4; ++i)
#pragma unroll
        for (int k = 0; k < 8; ++k) acc[i][k] = 0.f;

#pragma unroll
    for (int dy = -1; dy <= 1; ++dy) {
        const int yy = y + dy;
        if (yy < 0 || yy >= H) continue;
        const ushort_t* rp = tb + (ptrdiff_t)dy * W * C3;

        float f[6][8];
#pragma unroll
        for (int d = 0; d < 6; ++d) {
            const int xx = x0 + d - 1;
            if (xx < 0 || xx >= W) {
#pragma unroll
                for (int k = 0; k < 8; ++k) f[d][k] = 0.f;
            } else {
                const bf16x8 v = *(const bf16x8*)(rp + (ptrdiff_t)(d - 1) * C3);
#pragma unroll
                for (int k = 0; k < 8; ++k) f[d][k] = bfbits2f((ushort_t)v[k]);
            }
        }
#pragma unroll
        for (int k = 0; k < 8; ++k) {
            const float* wk = &wloc[(chloc + k) * 9 + (dy + 1) * 3];
            const float w0 = wk[0], w1 = wk[1], w2 = wk[2];
#pragma unroll
            for (int i = 0; i < 4; ++i)
                acc[i][k] += f[i][k] * w0 + f[i + 1][k] * w1 + f[i + 2][k] * w2;
        }
    }

    // stage to LDS [128][72]
#pragma unroll
    for (int i = 0; i < 4; ++i) {
        bf16x8 o;
#pragma unroll
        for (int k = 0; k < 8; ++k) o[k] = (short)f2bfbits(acc[i][k]);
        *(bf16x8*)&Ld[(pxl0 + i) * 72 + chloc] = o;
    }
    __syncthreads();

    // coalesced store: 8 lanes per px row (128B contiguous per px)
    const int pxl = tid >> 3, c8 = (tid & 7) * 8;
#pragma unroll
    for (int r = 0; r < 4; ++r) {
        const int p = r * 32 + pxl;
        const bf16x8 v = *(const bf16x8*)&Ld[p * 72 + c8];
        *(bf16x8*)(out + (size_t)(px_blk * 128 + p) * C3 + cb * 64 + c8) = v;
    }
}

// ---------------------------------------------------------------------------
// MFMA attention (R5 form): swapped QK^T, base-2 softmax, no Q/K LDS staging,
// 39424 B LDS -> 4 blocks/CU, 1-D grid with chunk-matched decode.
// ---------------------------------------------------------------------------
__global__ __launch_bounds__(256, 4) void attention_mfma_kernel(
    const ushort_t* __restrict__ qkv, const float* __restrict__ rpb,
    ushort_t* __restrict__ att)
{
    const int lin  = blockIdx.x;        // 0..1535
    const int xcd  = lin & 7;
    const int j    = lin >> 3;          // 0..191
    const int b    = xcd >> 2;
    const int y    = (xcd & 3) * 32 + (j & 31);
    const int head = j >> 5;            // 0..5
    const int t    = threadIdx.x;
    const int wv   = t >> 6;
    const int lane = t & 63;
    const int quad = lane >> 4;
    const int l16  = lane & 15;

    __shared__ __align__(16) char smem[39424];
    ushort_t* Vt = (ushort_t*)smem;               // [32][264]  = 16896 B
    ushort_t* Pb = (ushort_t*)(smem + 16896);     // [4][64][40]= 20480 B
    ushort_t* rb = (ushort_t*)(smem + 37376);     // [2][512]   =  2048 B
    float*    Ol = (float*)smem;                  // [32][257] epilogue overlay

    const size_t rowbase = ((size_t)b * HW + (size_t)y * W) * C3;
    const ushort_t* qbase = qkv + rowbase + head * HD + quad * 8;
    const ushort_t* kbase = qbase + C;

    // ---- stage V transposed into LDS; build base-2 rpb table (2 copies) ----
    {
        const ushort_t* rowp = qkv + rowbase + (size_t)t * C3 + head * HD;
        bf16x8 vfr[4];
#pragma unroll
        for (int g = 0; g < 4; ++g)
            vfr[g] = *(const bf16x8*)(rowp + 2 * C + g * 8);
#pragma unroll
        for (int g = 0; g < 4; ++g)
#pragma unroll
            for (int k = 0; k < 8; ++k)
                Vt[(g * 8 + k) * 264 + t] = (ushort_t)vfr[g][k];
    }
    {
        const float LOG2E = 1.4426950408889634f;
#pragma unroll
        for (int s2 = 0; s2 < 2; ++s2)
#pragma unroll
            for (int pp = 0; pp < 2; ++pp) {
                const int k = pp * 256 + t;
                const int src = k + s2;
                rb[s2 * 512 + k] =
                    f2bfbits(src <= 510 ? rpb[src * HEADS + head] * LOG2E : 0.f);
            }
    }

    // Q fragments (B-operand layout) direct from global; first K fragment.
    bf16x8 aQ[4];
#pragma unroll
    for (int rt = 0; rt < 4; ++rt)
        aQ[rt] = *(const bf16x8*)(qbase + (size_t)(wv * 64 + rt * 16 + l16) * C3);
    bf16x8 bK = *(const bf16x8*)(kbase + (size_t)l16 * C3);

    __syncthreads();

    ushort_t* PbW = Pb + wv * 2560;
    float lsum[4] = {0.f, 0.f, 0.f, 0.f};
    f32x4 o_acc[4][2];
#pragma unroll
    for (int rt = 0; rt < 4; ++rt)
#pragma unroll
        for (int ct = 0; ct < 2; ++ct)
            o_acc[rt][ct] = f32x4{0.f, 0.f, 0.f, 0.f};

    const int ibase = wv * 64 + l16 + 255 - quad * 4;

    for (int c2 = 0; c2 < 8; ++c2) {
#pragma unroll
        for (int half = 0; half < 2; ++half) {
            const int n  = c2 * 2 + half;
            const int nn = (n < 15) ? n + 1 : 15;
            const bf16x8 bKn =
                *(const bf16x8*)(kbase + (size_t)(nn * 16 + l16) * C3);
#pragma unroll
            for (int rt = 0; rt < 4; ++rt) {
                // bias^T: idx = i - j + 255 = (ibase + rt*16 - n*16) - reg
                const int a  = ibase + rt * 16 - n * 16 - 3;  // 0..507
                const int s2 = a & 1;
                const uint* tp = (const uint*)(rb + s2 * 512 + (a - s2));
                const uint u0 = tp[0], u1 = tp[1];  // rpb2[a..a+3]
                f32x4 s;
                s[0] = __uint_as_float(u1 & 0xffff0000u);
                s[1] = __uint_as_float(u1 << 16);
                s[2] = __uint_as_float(u0 & 0xffff0000u);
                s[3] = __uint_as_float(u0 << 16);
                s = __builtin_amdgcn_mfma_f32_16x16x32_bf16(bK, aQ[rt], s, 0, 0, 0);
                const float p0 = __builtin_amdgcn_exp2f(s[0]);
                const float p1 = __builtin_amdgcn_exp2f(s[1]);
                const float p2 = __builtin_amdgcn_exp2f(s[2]);
                const float p3 = __builtin_amdgcn_exp2f(s[3]);
                lsum[rt] += (p0 + p1) + (p2 + p3);
                uint2 dd;
                dd.x = (uint)f2bfbits(p0) | ((uint)f2bfbits(p1) << 16);
                dd.y = (uint)f2bfbits(p2) | ((uint)f2bfbits(p3) << 16);
                *(uint2*)&PbW[(rt * 16 + l16) * 40 + half * 16 + quad * 4] = dd;
            }
            bK = bKn;
        }
        // PV for this 32-wide j block
#pragma unroll
        for (int rt = 0; rt < 4; ++rt) {
            const bf16x8 aP = *(const bf16x8*)&PbW[(rt * 16 + l16) * 40 + quad * 8];
#pragma unroll
            for (int ct = 0; ct < 2; ++ct) {
                const bf16x8 bV = *(const bf16x8*)
                    &Vt[(ct * 16 + l16) * 264 + c2 * 32 + quad * 8];
                o_acc[rt][ct] = __builtin_amdgcn_mfma_f32_16x16x32_bf16(
                    aP, bV, o_acc[rt][ct], 0, 0, 0);
            }
        }
    }

    // softmax denominators: lane-local partial + reduce across quads
    float linv[4];
#pragma unroll
    for (int rt = 0; rt < 4; ++rt) {
        float v = lsum[rt];
        v += __shfl_xor(v, 16);
        v += __shfl_xor(v, 32);
        linv[rt] = 1.f / v;
    }

    __syncthreads();   // all waves done with Vt/Pb -> overlay Ol
#pragma unroll
    for (int rt = 0; rt < 4; ++rt) {
        const int i = wv * 64 + rt * 16 + quad * 4;
        float sc[4];
#pragma unroll
        for (int reg = 0; reg < 4; ++reg)
            sc[reg] = __shfl(linv[rt], quad * 4 + reg);
#pragma unroll
        for (int ct = 0; ct < 2; ++ct) {
            const int c = ct * 16 + l16;
#pragma unroll
            for (int reg = 0; reg < 4; ++reg)
                Ol[c * 257 + i + reg] = o_acc[rt][ct][reg] * sc[reg];
        }
    }
    __syncthreads();

    // coalesced store: 4 lanes per px row (64B contiguous per px)
    const size_t orow = (size_t)b * HW + (size_t)y * W;
    const int pxl = t >> 2, part = t & 3;
#pragma unroll
    for (int r = 0; r < 4; ++r) {
        const int px = r * 64 + pxl;
        bf16x8 o;
#pragma unroll
        for (int k = 0; k < 8; ++k)
            o[k] = (short)f2bfbits(Ol[(part * 8 + k) * 257 + px]);
        *(bf16x8*)(att + (orow + px) * C + head * HD + part * 8) = o;
    }
}

// ---------------------------------------------------------------------------
// conv2_fused (R5 geometry + proven fixes): out = ((att@w_pre)*gate)@w_out.
// 512 blocks x 128 px (32 px/wave), lb(256,3). B panel hoisted out of the
// ms-loop (one latency wall); Zw stride 204 (R9-proven: bank conflicts
// 491K -> 0). 52.2 KB LDS -> 3 blocks/CU. NT f32 stores.
// ---------------------------------------------------------------------------
__global__ __launch_bounds__(256, 3) void conv2_fused_kernel(
    const ushort_t* __restrict__ att_t, const ushort_t* __restrict__ gatep,
    const ushort_t* __restrict__ wpre, const ushort_t* __restrict__ wout,
    float* __restrict__ outp)
{
    const int lin = blockIdx.x;          // 0..511
    const int xcd = lin & 7;
    const int pin = lin >> 3;            // 0..63
    const int p0  = (xcd * 64 + pin) * 128;

    const int t  = threadIdx.x;
    const int wv = t >> 6, lane = t & 63, quad = lane >> 4, l16 = lane & 15;

    __shared__ ushort_t Zs[4][32 * 204];   // 52.2 KB, per-wave scratch
    ushort_t* Zw = Zs[wv];
    const int pxw = p0 + wv * 32;

    // ---- B panel (att rows) loaded ONCE for all 3 ms blocks ----
    const ushort_t* bp = att_t + (size_t)(pxw + l16) * C + quad * 8;
    bf16x8 bB[6][2];
#pragma unroll
    for (int ks = 0; ks < 6; ++ks) {
        bB[ks][0] = *(const bf16x8*)(bp + ks * 32);
        bB[ks][1] = *(const bf16x8*)(bp + (size_t)16 * C + ks * 32);
    }

    // ---------- phase 1: z = (att @ w_pre) * gate ----------
#pragma unroll
    for (int ms = 0; ms < 3; ++ms) {
        f32x4 acc[4][2];
#pragma unroll
        for (int rt = 0; rt < 4; ++rt)
#pragma unroll
            for (int ct = 0; ct < 2; ++ct) acc[rt][ct] = f32x4{0.f,0.f,0.f,0.f};

        const ushort_t* ap = wpre + (size_t)(ms * 64 + l16) * C + quad * 8;
#pragma unroll
        for (int h = 0; h < 2; ++h) {
            bf16x8 aF[3][4];
#pragma unroll
            for (int k2 = 0; k2 < 3; ++k2)
#pragma unroll
                for (int rt = 0; rt < 4; ++rt)
                    aF[k2][rt] = *(const bf16x8*)(ap + (size_t)(rt * 16) * C +
                                                  (h * 3 + k2) * 32);
#pragma unroll
            for (int k2 = 0; k2 < 3; ++k2)
#pragma unroll
                for (int rt = 0; rt < 4; ++rt) {
                    acc[rt][0] = __builtin_amdgcn_mfma_f32_16x16x32_bf16(
                        aF[k2][rt], bB[h * 3 + k2][0], acc[rt][0], 0, 0, 0);
                    acc[rt][1] = __builtin_amdgcn_mfma_f32_16x16x32_bf16(
                        aF[k2][rt], bB[h * 3 + k2][1], acc[rt][1], 0, 0, 0);
                }
        }

        // gate multiply + z -> per-wave LDS
#pragma unroll
        for (int rt = 0; rt < 4; ++rt)
#pragma unroll
            for (int ct = 0; ct < 2; ++ct) {
                const int px = pxw + ct * 16 + l16;
                const int ch = ms * 64 + rt * 16 + quad * 4;
                const ushort4 g = *(const ushort4*)(gatep + (size_t)px * C + ch);
                f32x4 v = acc[rt][ct];
                v[0] *= bfbits2f(g.x); v[1] *= bfbits2f(g.y);
                v[2] *= bfbits2f(g.z); v[3] *= bfbits2f(g.w);
                ushort4 o;
                o.x = f2bfbits(v[0]); o.y = f2bfbits(v[1]);
                o.z = f2bfbits(v[2]); o.w = f2bfbits(v[3]);
                *(ushort4*)&Zw[(ct * 16 + l16) * 204 + ch] = o;
            }
    }

    // ---------- phase 2: out = z @ w_out (f32 ch-major, non-temporal) ------
    const int bb  = p0 >> 15;
    const int hwb = (p0 & (HW - 1)) + wv * 32;
#pragma unroll
    for (int ms = 0; ms < 3; ++ms) {
        f32x4 acc[4][2];
#pragma unroll
        for (int rt = 0; rt < 4; ++rt)
#pragma unroll
            for (int ct = 0; ct < 2; ++ct) acc[rt][ct] = f32x4{0.f,0.f,0.f,0.f};

        const ushort_t* ap = wout + (size_t)(ms * 64 + l16) * C + quad * 8;
#pragma unroll
        for (int h = 0; h < 2; ++h) {
            bf16x8 aF[3][4];
#pragma unroll
            for (int k2 = 0; k2 < 3; ++k2)
#pragma unroll
                for (int rt = 0; rt < 4; ++rt)
                    aF[k2][rt] = *(const bf16x8*)(ap + (size_t)(rt * 16) * C +
                                                  (h * 3 + k2) * 32);
#pragma unroll
            for (int k2 = 0; k2 < 3; ++k2) {
                const int ks = h * 3 + k2;
                const bf16x8 b0 = *(const bf16x8*)&Zw[l16 * 204 + quad * 8 + ks * 32];
                const bf16x8 b1 = *(const bf16x8*)&Zw[(16 + l16) * 204 + quad * 8 + ks * 32];
#pragma unroll
                for (int rt = 0; rt < 4; ++rt) {
                    acc[rt][0] = __builtin_amdgcn_mfma_f32_16x16x32_bf16(
                        aF[k2][rt], b0, acc[rt][0], 0, 0, 0);
                    acc[rt][1] = __builtin_amdgcn_mfma_f32_16x16x32_bf16(
                        aF[k2][rt], b1, acc[rt][1], 0, 0, 0);
                }
            }
        }
        float* ob = outp + ((size_t)bb * C + ms * 64) * HW + hwb;
#pragma unroll
        for (int rt = 0; rt < 4; ++rt)
#pragma unroll
            for (int ct = 0; ct < 2; ++ct) {
                const f32x4 v = acc[rt][ct];
#pragma unroll
                for (int r = 0; r < 4; ++r)
                    __builtin_nontemporal_store(v[r],
                        &ob[(size_t)(rt * 16 + quad * 4 + r) * HW + ct * 16 + l16]);
            }
    }
}

// ---------------------------------------------------------------------------
extern "C" void kernel_launch(void* const* d_in, const int* in_sizes, int n_in,
                              void* d_out, int out_size, void* d_ws, size_t ws_size,
                              hipStream_t stream)
{
    const float* x       = (const float*)d_in[0];
    const float* rpb     = (const float*)d_in[1];
    const float* w_qkv   = (const float*)d_in[2];
    const float* w_depth = (const float*)d_in[3];
    const float* w_pre   = (const float*)d_in[4];
    const float* w_out   = (const float*)d_in[5];
    const float* w_gate  = (const float*)d_in[6];
    float* out = (float*)d_out;

    // workspace layout, aliased by lifetime:
    char* wsb = (char*)d_ws;
    ushort_t* wbf      = (ushort_t*)wsb;           // qkv|gate|pre|out rows
    ushort_t* w_pre_b  = wbf + 147456;
    ushort_t* w_out_b  = wbf + 184320;
    ushort_t* gate_t   = (ushort_t*)(wsb + 524288u);
    ushort_t* buf_t    = (ushort_t*)(wsb + 25690112u);
    ushort_t* att_t    = (ushort_t*)(wsb + 25690112u);
    ushort_t* buf_qkv  = (ushort_t*)(wsb + 101187584u);
    ushort_t* x_t      = (ushort_t*)(wsb + 101187584u);

    dim3 blk(256);

    prep_w_kernel<<<dim3(216), blk, 0, stream>>>(w_qkv, w_gate, w_pre, w_out, wbf);
    transpose_x_kernel<<<dim3(NPX / 64), blk, 0, stream>>>(x, x_t);
    // buf_t = x_t @ w_qkv (q pre-scaled), gate_t = silu(x_t @ w_gate)
    conv_mfma_kernel<3, 0, 12><<<dim3(3072), blk, 0, stream>>>(
        x_t, wbf, buf_t, gate_t, C3);
    // qkv = depthwise3x3(t)                   px-major bf16 [px][576]
    dwconv3x3_px_kernel<<<dim3(NPX / 128, 9), blk, 0, stream>>>(
        buf_t, w_depth, buf_qkv);
    // att_t = attention(qkv, rpb)             px-major bf16
    attention_mfma_kernel<<<dim3(H * HEADS * BATCH), blk, 0, stream>>>(
        buf_qkv, rpb, att_t);
    // out = ((att_t @ w_pre) * gate_t) @ w_out   (fused, f32 ch-major)
    conv2_fused_kernel<<<dim3(NPX / 128), blk, 0, stream>>>(
        att_t, gate_t, w_pre_b, w_out_b, out);
}

// Round 11
// 285.246 us; speedup vs baseline: 1.4685x; 1.0287x over previous
//
#include <hip/hip_runtime.h>
#include <hip/hip_bf16.h>
#include <math.h>

#define BATCH 2
#define C 192
#define H 128
#define W 256
#define HEADS 6
#define HD 32
#define HW (H * W)      // 32768
#define C3 (3 * C)      // 576
#define NPX (BATCH * HW)  // 65536

typedef unsigned short ushort_t;
using bf16x8 = __attribute__((ext_vector_type(8))) short;
using f32x4  = __attribute__((ext_vector_type(4))) float;

static __device__ __forceinline__ float bfbits2f(ushort_t u) {
    return __uint_as_float(((unsigned)u) << 16);
}
static __device__ __forceinline__ ushort_t f2bfbits(float f) {
    __hip_bfloat16 h = __float2bfloat16(f);
    return *reinterpret_cast<ushort_t*>(&h);
}

// ---------------------------------------------------------------------------
// prep_w: fp32 -> bf16 weights; q-rows of w_qkv pre-scaled by 32^-0.5*log2(e).
// Layout: w_qkv rows 0..575 | w_gate rows 576..767 | w_pre | w_out.
// ---------------------------------------------------------------------------
__global__ __launch_bounds__(256) void prep_w_kernel(
    const float* __restrict__ wq, const float* __restrict__ wg,
    const float* __restrict__ wp, const float* __restrict__ wo,
    ushort_t* __restrict__ dst)
{
    const int i = blockIdx.x * 256 + threadIdx.x;   // float4 index, < 55296
    const float* src; int off, base;
    if (i < 27648)      { src = wq; off = i;         base = 0; }
    else if (i < 36864) { src = wg; off = i - 27648; base = 110592; }
    else if (i < 46080) { src = wp; off = i - 36864; base = 147456; }
    else                { src = wo; off = i - 46080; base = 184320; }
    float4 v = ((const float4*)src)[off];
    if (i < 9216) {   // w_qkv rows 0..191 (the q projection)
        const float sc = 0.25503488f;   // 32^-0.5 * log2(e)
        v.x *= sc; v.y *= sc; v.z *= sc; v.w *= sc;
    }
    ushort4 o;
    o.x = f2bfbits(v.x); o.y = f2bfbits(v.y);
    o.z = f2bfbits(v.z); o.w = f2bfbits(v.w);
    *(ushort4*)(dst + base + off * 4) = o;
}

// ---------------------------------------------------------------------------
// transpose_x: x [B][192][HW] f32 -> x_t [B*HW][192] bf16 (pixel-major).
// ---------------------------------------------------------------------------
__global__ __launch_bounds__(256) void transpose_x_kernel(
    const float* __restrict__ x, ushort_t* __restrict__ xt)
{
    __shared__ uint Xs[64 * 97];   // 24.8 KB
    const int p0 = blockIdx.x * 64;
    const int b  = p0 >> 15, hw0 = p0 & (HW - 1);
    const int t  = threadIdx.x;

    {
        const int px = t & 63, g = t >> 6;
        const float* xb = x + (size_t)b * C * HW + hw0 + px;
#pragma unroll
        for (int i = 0; i < 24; ++i) {
            const int cp = g + i * 4;   // channel pair 0..95
            const float v0 = xb[(size_t)(2 * cp) * HW];
            const float v1 = xb[(size_t)(2 * cp + 1) * HW];
            Xs[px * 97 + cp] = (uint)f2bfbits(v0) | ((uint)f2bfbits(v1) << 16);
        }
    }
    __syncthreads();
    {
        const int px = t >> 2, grp = t & 3;
        uint* dst = (uint*)(xt + (size_t)(p0 + px) * C) + grp * 24;
        const uint* s = &Xs[px * 97 + grp * 24];
#pragma unroll
        for (int i = 0; i < 6; ++i) {
            uint4 u;
            u.x = s[i * 4 + 0]; u.y = s[i * 4 + 1];
            u.z = s[i * 4 + 2]; u.w = s[i * 4 + 3];
            *(uint4*)(dst + i * 4) = u;
        }
    }
}

// ---------------------------------------------------------------------------
// MFMA conv1x1 GEMM (byte-identical R4 form — best measured, 52.4 us).
// Block: 4 waves; tile M=64 x N=256, K=192; As/Ls overlay in one 36.9 KB
// buffer; LDS-coalesced px-major stores. launch_bounds(256,2).
// MODE 3 (only instantiation): fused qkv+gate, MT=12: m 0..8 -> buf_t
// [px][576]; m 9..11 -> silu -> gate [px][192]. Chunk map xcd = px/8192.
// ---------------------------------------------------------------------------
template <int MODE, int OUTKIND, int MT>
__global__ __launch_bounds__(256, 2) void conv_mfma_kernel(
    const ushort_t* __restrict__ in_t, const ushort_t* __restrict__ w_bf,
    void* __restrict__ outp, ushort_t* __restrict__ gate, int ostride)
{
    const int lin = blockIdx.x;
    const int xcd = lin & 7;
    const int jj  = lin >> 3;
    const int pin = jj / MT;            // 0..31
    const int m   = jj - pin * MT;      // 0..MT-1
    const int m0  = m * 64;
    const int p0  = (xcd * 32 + pin) * 256;

    const int t  = threadIdx.x;
    const int wv = t >> 6, lane = t & 63, quad = lane >> 4, l16 = lane & 15;

    // As 64x200 (25.6KB) / Ls 256x72 (36.9KB) share this by lifetime.
    __shared__ ushort_t smem[18432];
    ushort_t* As = smem;

    // ---- issue the wave's B panel (24x 16B gathers) ----
    const ushort_t* bp = in_t + (size_t)(p0 + wv * 64 + l16) * C + quad * 8;
    bf16x8 bF[6][4];
#pragma unroll
    for (int ks = 0; ks < 6; ++ks)
#pragma unroll
        for (int ct = 0; ct < 4; ++ct)
            bF[ks][ct] = *(const bf16x8*)(bp + (size_t)(ct * 16) * C + ks * 32);

    // ---- stage A (weights m0..m0+63 x 192) into LDS, padded to 200 ----
    {
        const int row = t >> 2, cg = (t & 3) * 48;
        const ushort_t* src = w_bf + (size_t)(m0 + row) * C + cg;
        ushort_t* dst = &As[row * 200 + cg];
#pragma unroll
        for (int i = 0; i < 6; ++i)
            *(bf16x8*)(dst + i * 8) = *(const bf16x8*)(src + i * 8);
    }
    __syncthreads();

    f32x4 acc[4][4];
#pragma unroll
    for (int rt = 0; rt < 4; ++rt)
#pragma unroll
        for (int ct = 0; ct < 4; ++ct) acc[rt][ct] = f32x4{0.f, 0.f, 0.f, 0.f};

    // ---- MFMA loop ----
#pragma unroll
    for (int ks = 0; ks < 6; ++ks) {
        bf16x8 aF[4];
#pragma unroll
        for (int rt = 0; rt < 4; ++rt)
            aF[rt] = *(const bf16x8*)&As[(rt * 16 + l16) * 200 + quad * 8 + ks * 32];
#pragma unroll
        for (int rt = 0; rt < 4; ++rt)
#pragma unroll
            for (int ct = 0; ct < 4; ++ct)
                acc[rt][ct] = __builtin_amdgcn_mfma_f32_16x16x32_bf16(
                    aF[rt], bF[ks][ct], acc[rt][ct], 0, 0, 0);
    }

    // ---- per-lane epilogue transforms ----
    const bool isg = (MODE == 3) && (m >= 9);   // gate block of fused kernel
    if (MODE == 1 || isg) {
#pragma unroll
        for (int rt = 0; rt < 4; ++rt)
#pragma unroll
            for (int ct = 0; ct < 4; ++ct) {
                f32x4 v = acc[rt][ct];
#pragma unroll
                for (int r = 0; r < 4; ++r)
                    v[r] = v[r] / (1.f + __expf(-v[r]));
                acc[rt][ct] = v;
            }
    }

    if constexpr (OUTKIND == 0) {
        // ---- LDS-transposed coalesced store ----
        __syncthreads();                 // all As reads complete
        ushort_t* Ls = smem;             // [256][72]
#pragma unroll
        for (int rt = 0; rt < 4; ++rt)
#pragma unroll
            for (int ct = 0; ct < 4; ++ct) {
                const f32x4 v = acc[rt][ct];
                ushort4 o;
                o.x = f2bfbits(v[0]); o.y = f2bfbits(v[1]);
                o.z = f2bfbits(v[2]); o.w = f2bfbits(v[3]);
                *(ushort4*)&Ls[(wv * 64 + ct * 16 + l16) * 72 +
                               rt * 16 + quad * 4] = o;
            }
        __syncthreads();

        ushort_t* ob; int osr, chb;
        if constexpr (MODE == 3) {
            ob  = isg ? gate : (ushort_t*)outp;
            osr = isg ? C : C3;
            chb = isg ? m0 - C3 : m0;
        } else {
            ob = (ushort_t*)outp; osr = ostride; chb = m0;
        }
        const int pxl = t >> 3, c8 = (t & 7) * 8;
#pragma unroll
        for (int r = 0; r < 8; ++r) {
            const int px = r * 32 + pxl;
            const bf16x8 v = *(const bf16x8*)&Ls[px * 72 + c8];
            *(bf16x8*)(ob + (size_t)(p0 + px) * osr + chb + c8) = v;
        }
    } else {
        const int bb = p0 >> 15;
        const int hwb = (p0 & (HW - 1)) + wv * 64;
        float* ob = (float*)outp + ((size_t)bb * C + m0) * HW + hwb;
#pragma unroll
        for (int rt = 0; rt < 4; ++rt)
#pragma unroll
            for (int ct = 0; ct < 4; ++ct) {
                const f32x4 v = acc[rt][ct];
#pragma unroll
                for (int r = 0; r < 4; ++r)
                    ob[(size_t)(rt * 16 + quad * 4 + r) * HW + ct * 16 + l16] = v[r];
            }
    }
}

// ---------------------------------------------------------------------------
// depthwise 3x3, pixel-major, LDS-coalesced stores (R5 form, uncapped).
// Chunk swizzle xcd = px/8192, reversed within-chunk.
// ---------------------------------------------------------------------------
__global__ __launch_bounds__(256) void dwconv3x3_px_kernel(
    const ushort_t* __restrict__ tin, const float* __restrict__ wd,
    ushort_t* __restrict__ out)
{
    __shared__ float wloc[576];
    __shared__ ushort_t Ld[128 * 72];   // 18.4 KB
    const int bx = blockIdx.x;                       // 0..511
    const int px_blk = (bx & 7) * 64 + (63 - (bx >> 3));
    const int cb  = blockIdx.y;
    const int tid = threadIdx.x;
    if (tid < 144)
        *(float4*)&wloc[tid * 4] = *(const float4*)(wd + cb * 576 + tid * 4);
    __syncthreads();

    const int chloc = (tid & 7) * 8;
    const int pxl0 = (tid >> 3) * 4;               // local px 0..124
    const int px = px_blk * 128 + pxl0;
    const int x0 = px & (W - 1);
    const int y  = (px >> 8) & (H - 1);

    const ushort_t* tb = tin + (size_t)px * C3 + cb * 64 + chloc;

    float acc[4][8];
#pragma unroll
    for (int i = 0; i < 4; ++i)
#pragma unroll
        for (int k = 0; k < 8; ++k) acc[i][k] = 0.f;

#pragma unroll
    for (int dy = -1; dy <= 1; ++dy) {
        const int yy = y + dy;
        if (yy < 0 || yy >= H) continue;
        const ushort_t* rp = tb + (ptrdiff_t)dy * W * C3;

        float f[6][8];
#pragma unroll
        for (int d = 0; d < 6; ++d) {
            const int xx = x0 + d - 1;
            if (xx < 0 || xx >= W) {
#pragma unroll
                for (int k = 0; k < 8; ++k) f[d][k] = 0.f;
            } else {
                const bf16x8 v = *(const bf16x8*)(rp + (ptrdiff_t)(d - 1) * C3);
#pragma unroll
                for (int k = 0; k < 8; ++k) f[d][k] = bfbits2f((ushort_t)v[k]);
            }
        }
#pragma unroll
        for (int k = 0; k < 8; ++k) {
            const float* wk = &wloc[(chloc + k) * 9 + (dy + 1) * 3];
            const float w0 = wk[0], w1 = wk[1], w2 = wk[2];
#pragma unroll
            for (int i = 0; i < 4; ++i)
                acc[i][k] += f[i][k] * w0 + f[i + 1][k] * w1 + f[i + 2][k] * w2;
        }
    }

    // stage to LDS [128][72]
#pragma unroll
    for (int i = 0; i < 4; ++i) {
        bf16x8 o;
#pragma unroll
        for (int k = 0; k < 8; ++k) o[k] = (short)f2bfbits(acc[i][k]);
        *(bf16x8*)&Ld[(pxl0 + i) * 72 + chloc] = o;
    }
    __syncthreads();

    // coalesced store: 8 lanes per px row (128B contiguous per px)
    const int pxl = tid >> 3, c8 = (tid & 7) * 8;
#pragma unroll
    for (int r = 0; r < 4; ++r) {
        const int p = r * 32 + pxl;
        const bf16x8 v = *(const bf16x8*)&Ld[p * 72 + c8];
        *(bf16x8*)(out + (size_t)(px_blk * 128 + p) * C3 + cb * 64 + c8) = v;
    }
}

// ---------------------------------------------------------------------------
// MFMA attention (R5 form): swapped QK^T, base-2 softmax, no Q/K LDS staging,
// 39424 B LDS -> 4 blocks/CU, 1-D grid with chunk-matched decode.
// ---------------------------------------------------------------------------
__global__ __launch_bounds__(256, 4) void attention_mfma_kernel(
    const ushort_t* __restrict__ qkv, const float* __restrict__ rpb,
    ushort_t* __restrict__ att)
{
    const int lin  = blockIdx.x;        // 0..1535
    const int xcd  = lin & 7;
    const int j    = lin >> 3;          // 0..191
    const int b    = xcd >> 2;
    const int y    = (xcd & 3) * 32 + (j & 31);
    const int head = j >> 5;            // 0..5
    const int t    = threadIdx.x;
    const int wv   = t >> 6;
    const int lane = t & 63;
    const int quad = lane >> 4;
    const int l16  = lane & 15;

    __shared__ __align__(16) char smem[39424];
    ushort_t* Vt = (ushort_t*)smem;               // [32][264]  = 16896 B
    ushort_t* Pb = (ushort_t*)(smem + 16896);     // [4][64][40]= 20480 B
    ushort_t* rb = (ushort_t*)(smem + 37376);     // [2][512]   =  2048 B
    float*    Ol = (float*)smem;                  // [32][257] epilogue overlay

    const size_t rowbase = ((size_t)b * HW + (size_t)y * W) * C3;
    const ushort_t* qbase = qkv + rowbase + head * HD + quad * 8;
    const ushort_t* kbase = qbase + C;

    // ---- stage V transposed into LDS; build base-2 rpb table (2 copies) ----
    {
        const ushort_t* rowp = qkv + rowbase + (size_t)t * C3 + head * HD;
        bf16x8 vfr[4];
#pragma unroll
        for (int g = 0; g < 4; ++g)
            vfr[g] = *(const bf16x8*)(rowp + 2 * C + g * 8);
#pragma unroll
        for (int g = 0; g < 4; ++g)
#pragma unroll
            for (int k = 0; k < 8; ++k)
                Vt[(g * 8 + k) * 264 + t] = (ushort_t)vfr[g][k];
    }
    {
        const float LOG2E = 1.4426950408889634f;
#pragma unroll
        for (int s2 = 0; s2 < 2; ++s2)
#pragma unroll
            for (int pp = 0; pp < 2; ++pp) {
                const int k = pp * 256 + t;
                const int src = k + s2;
                rb[s2 * 512 + k] =
                    f2bfbits(src <= 510 ? rpb[src * HEADS + head] * LOG2E : 0.f);
            }
    }

    // Q fragments (B-operand layout) direct from global; first K fragment.
    bf16x8 aQ[4];
#pragma unroll
    for (int rt = 0; rt < 4; ++rt)
        aQ[rt] = *(const bf16x8*)(qbase + (size_t)(wv * 64 + rt * 16 + l16) * C3);
    bf16x8 bK = *(const bf16x8*)(kbase + (size_t)l16 * C3);

    __syncthreads();

    ushort_t* PbW = Pb + wv * 2560;
    float lsum[4] = {0.f, 0.f, 0.f, 0.f};
    f32x4 o_acc[4][2];
#pragma unroll
    for (int rt = 0; rt < 4; ++rt)
#pragma unroll
        for (int ct = 0; ct < 2; ++ct)
            o_acc[rt][ct] = f32x4{0.f, 0.f, 0.f, 0.f};

    const int ibase = wv * 64 + l16 + 255 - quad * 4;

    for (int c2 = 0; c2 < 8; ++c2) {
#pragma unroll
        for (int half = 0; half < 2; ++half) {
            const int n  = c2 * 2 + half;
            const int nn = (n < 15) ? n + 1 : 15;
            const bf16x8 bKn =
                *(const bf16x8*)(kbase + (size_t)(nn * 16 + l16) * C3);
#pragma unroll
            for (int rt = 0; rt < 4; ++rt) {
                // bias^T: idx = i - j + 255 = (ibase + rt*16 - n*16) - reg
                const int a  = ibase + rt * 16 - n * 16 - 3;  // 0..507
                const int s2 = a & 1;
                const uint* tp = (const uint*)(rb + s2 * 512 + (a - s2));
                const uint u0 = tp[0], u1 = tp[1];  // rpb2[a..a+3]
                f32x4 s;
                s[0] = __uint_as_float(u1 & 0xffff0000u);
                s[1] = __uint_as_float(u1 << 16);
                s[2] = __uint_as_float(u0 & 0xffff0000u);
                s[3] = __uint_as_float(u0 << 16);
                s = __builtin_amdgcn_mfma_f32_16x16x32_bf16(bK, aQ[rt], s, 0, 0, 0);
                const float p0 = __builtin_amdgcn_exp2f(s[0]);
                const float p1 = __builtin_amdgcn_exp2f(s[1]);
                const float p2 = __builtin_amdgcn_exp2f(s[2]);
                const float p3 = __builtin_amdgcn_exp2f(s[3]);
                lsum[rt] += (p0 + p1) + (p2 + p3);
                uint2 dd;
                dd.x = (uint)f2bfbits(p0) | ((uint)f2bfbits(p1) << 16);
                dd.y = (uint)f2bfbits(p2) | ((uint)f2bfbits(p3) << 16);
                *(uint2*)&PbW[(rt * 16 + l16) * 40 + half * 16 + quad * 4] = dd;
            }
            bK = bKn;
        }
        // PV for this 32-wide j block
#pragma unroll
        for (int rt = 0; rt < 4; ++rt) {
            const bf16x8 aP = *(const bf16x8*)&PbW[(rt * 16 + l16) * 40 + quad * 8];
#pragma unroll
            for (int ct = 0; ct < 2; ++ct) {
                const bf16x8 bV = *(const bf16x8*)
                    &Vt[(ct * 16 + l16) * 264 + c2 * 32 + quad * 8];
                o_acc[rt][ct] = __builtin_amdgcn_mfma_f32_16x16x32_bf16(
                    aP, bV, o_acc[rt][ct], 0, 0, 0);
            }
        }
    }

    // softmax denominators: lane-local partial + reduce across quads
    float linv[4];
#pragma unroll
    for (int rt = 0; rt < 4; ++rt) {
        float v = lsum[rt];
        v += __shfl_xor(v, 16);
        v += __shfl_xor(v, 32);
        linv[rt] = 1.f / v;
    }

    __syncthreads();   // all waves done with Vt/Pb -> overlay Ol
#pragma unroll
    for (int rt = 0; rt < 4; ++rt) {
        const int i = wv * 64 + rt * 16 + quad * 4;
        float sc[4];
#pragma unroll
        for (int reg = 0; reg < 4; ++reg)
            sc[reg] = __shfl(linv[rt], quad * 4 + reg);
#pragma unroll
        for (int ct = 0; ct < 2; ++ct) {
            const int c = ct * 16 + l16;
#pragma unroll
            for (int reg = 0; reg < 4; ++reg)
                Ol[c * 257 + i + reg] = o_acc[rt][ct][reg] * sc[reg];
        }
    }
    __syncthreads();

    // coalesced store: 4 lanes per px row (64B contiguous per px)
    const size_t orow = (size_t)b * HW + (size_t)y * W;
    const int pxl = t >> 2, part = t & 3;
#pragma unroll
    for (int r = 0; r < 4; ++r) {
        const int px = r * 64 + pxl;
        bf16x8 o;
#pragma unroll
        for (int k = 0; k < 8; ++k)
            o[k] = (short)f2bfbits(Ol[(part * 8 + k) * 257 + px]);
        *(bf16x8*)(att + (orow + px) * C + head * HD + part * 8) = o;
    }
}

// ---------------------------------------------------------------------------
// conv2_fused (R5 inner structure; stride 200 -> 208). 512 blocks x 128 px
// (32 px/wave), lb(256,3). Zw stride 208 ushorts = 416 B: keeps 16B
// alignment (R10's 204 broke it) while cutting the phase-2 ds_read_b128
// conflict from 8-way to 4-way (row bank-shift 8 dwords instead of 4).
// LDS 53,248 B -> 3 blocks/CU (159.7 KB). NT f32 stores.
// ---------------------------------------------------------------------------
__global__ __launch_bounds__(256, 3) void conv2_fused_kernel(
    const ushort_t* __restrict__ att_t, const ushort_t* __restrict__ gatep,
    const ushort_t* __restrict__ wpre, const ushort_t* __restrict__ wout,
    float* __restrict__ outp)
{
    const int lin = blockIdx.x;          // 0..511
    const int xcd = lin & 7;
    const int pin = lin >> 3;            // 0..63
    const int p0  = (xcd * 64 + pin) * 128;

    const int t  = threadIdx.x;
    const int wv = t >> 6, lane = t & 63, quad = lane >> 4, l16 = lane & 15;

    __shared__ ushort_t Zs[4][32 * 208];   // 53.2 KB, per-wave scratch
    ushort_t* Zw = Zs[wv];
    const int pxw = p0 + wv * 32;

    // ---------- phase 1: z = (att @ w_pre) * gate ----------
#pragma unroll
    for (int ms = 0; ms < 3; ++ms) {
        f32x4 acc[4][2];
#pragma unroll
        for (int rt = 0; rt < 4; ++rt)
#pragma unroll
            for (int ct = 0; ct < 2; ++ct) acc[rt][ct] = f32x4{0.f,0.f,0.f,0.f};

        const ushort_t* ap = wpre + (size_t)(ms * 64 + l16) * C + quad * 8;
        const ushort_t* bp = att_t + (size_t)(pxw + l16) * C + quad * 8;
#pragma unroll
        for (int ks = 0; ks < 6; ++ks) {
            bf16x8 aF[4];
#pragma unroll
            for (int rt = 0; rt < 4; ++rt)
                aF[rt] = *(const bf16x8*)(ap + (size_t)(rt * 16) * C + ks * 32);
            const bf16x8 b0 = *(const bf16x8*)(bp + ks * 32);
            const bf16x8 b1 = *(const bf16x8*)(bp + (size_t)16 * C + ks * 32);
#pragma unroll
            for (int rt = 0; rt < 4; ++rt) {
                acc[rt][0] = __builtin_amdgcn_mfma_f32_16x16x32_bf16(
                    aF[rt], b0, acc[rt][0], 0, 0, 0);
                acc[rt][1] = __builtin_amdgcn_mfma_f32_16x16x32_bf16(
                    aF[rt], b1, acc[rt][1], 0, 0, 0);
            }
        }
        // gate multiply + z -> per-wave LDS
#pragma unroll
        for (int rt = 0; rt < 4; ++rt)
#pragma unroll
            for (int ct = 0; ct < 2; ++ct) {
                const int px = pxw + ct * 16 + l16;
                const int ch = ms * 64 + rt * 16 + quad * 4;
                const ushort4 g = *(const ushort4*)(gatep + (size_t)px * C + ch);
                f32x4 v = acc[rt][ct];
                v[0] *= bfbits2f(g.x); v[1] *= bfbits2f(g.y);
                v[2] *= bfbits2f(g.z); v[3] *= bfbits2f(g.w);
                ushort4 o;
                o.x = f2bfbits(v[0]); o.y = f2bfbits(v[1]);
                o.z = f2bfbits(v[2]); o.w = f2bfbits(v[3]);
                *(ushort4*)&Zw[(ct * 16 + l16) * 208 + ch] = o;
            }
    }

    // ---------- phase 2: out = z @ w_out (f32 ch-major, non-temporal) ------
    const int bb  = p0 >> 15;
    const int hwb = (p0 & (HW - 1)) + wv * 32;
#pragma unroll
    for (int ms = 0; ms < 3; ++ms) {
        f32x4 acc[4][2];
#pragma unroll
        for (int rt = 0; rt < 4; ++rt)
#pragma unroll
            for (int ct = 0; ct < 2; ++ct) acc[rt][ct] = f32x4{0.f,0.f,0.f,0.f};

        const ushort_t* ap = wout + (size_t)(ms * 64 + l16) * C + quad * 8;
#pragma unroll
        for (int ks = 0; ks < 6; ++ks) {
            bf16x8 aF[4];
#pragma unroll
            for (int rt = 0; rt < 4; ++rt)
                aF[rt] = *(const bf16x8*)(ap + (size_t)(rt * 16) * C + ks * 32);
            const bf16x8 b0 = *(const bf16x8*)&Zw[l16 * 208 + quad * 8 + ks * 32];
            const bf16x8 b1 = *(const bf16x8*)&Zw[(16 + l16) * 208 + quad * 8 + ks * 32];
#pragma unroll
            for (int rt = 0; rt < 4; ++rt) {
                acc[rt][0] = __builtin_amdgcn_mfma_f32_16x16x32_bf16(
                    aF[rt], b0, acc[rt][0], 0, 0, 0);
                acc[rt][1] = __builtin_amdgcn_mfma_f32_16x16x32_bf16(
                    aF[rt], b1, acc[rt][1], 0, 0, 0);
            }
        }
        float* ob = outp + ((size_t)bb * C + ms * 64) * HW + hwb;
#pragma unroll
        for (int rt = 0; rt < 4; ++rt)
#pragma unroll
            for (int ct = 0; ct < 2; ++ct) {
                const f32x4 v = acc[rt][ct];
#pragma unroll
                for (int r = 0; r < 4; ++r)
                    __builtin_nontemporal_store(v[r],
                        &ob[(size_t)(rt * 16 + quad * 4 + r) * HW + ct * 16 + l16]);
            }
    }
}

// ---------------------------------------------------------------------------
extern "C" void kernel_launch(void* const* d_in, const int* in_sizes, int n_in,
                              void* d_out, int out_size, void* d_ws, size_t ws_size,
                              hipStream_t stream)
{
    const float* x       = (const float*)d_in[0];
    const float* rpb     = (const float*)d_in[1];
    const float* w_qkv   = (const float*)d_in[2];
    const float* w_depth = (const float*)d_in[3];
    const float* w_pre   = (const float*)d_in[4];
    const float* w_out   = (const float*)d_in[5];
    const float* w_gate  = (const float*)d_in[6];
    float* out = (float*)d_out;

    // workspace layout, aliased by lifetime:
    char* wsb = (char*)d_ws;
    ushort_t* wbf      = (ushort_t*)wsb;           // qkv|gate|pre|out rows
    ushort_t* w_pre_b  = wbf + 147456;
    ushort_t* w_out_b  = wbf + 184320;
    ushort_t* gate_t   = (ushort_t*)(wsb + 524288u);
    ushort_t* buf_t    = (ushort_t*)(wsb + 25690112u);
    ushort_t* att_t    = (ushort_t*)(wsb + 25690112u);
    ushort_t* buf_qkv  = (ushort_t*)(wsb + 101187584u);
    ushort_t* x_t      = (ushort_t*)(wsb + 101187584u);

    dim3 blk(256);

    prep_w_kernel<<<dim3(216), blk, 0, stream>>>(w_qkv, w_gate, w_pre, w_out, wbf);
    transpose_x_kernel<<<dim3(NPX / 64), blk, 0, stream>>>(x, x_t);
    // buf_t = x_t @ w_qkv (q pre-scaled), gate_t = silu(x_t @ w_gate)
    conv_mfma_kernel<3, 0, 12><<<dim3(3072), blk, 0, stream>>>(
        x_t, wbf, buf_t, gate_t, C3);
    // qkv = depthwise3x3(t)                   px-major bf16 [px][576]
    dwconv3x3_px_kernel<<<dim3(NPX / 128, 9), blk, 0, stream>>>(
        buf_t, w_depth, buf_qkv);
    // att_t = attention(qkv, rpb)             px-major bf16
    attention_mfma_kernel<<<dim3(H * HEADS * BATCH), blk, 0, stream>>>(
        buf_qkv, rpb, att_t);
    // out = ((att_t @ w_pre) * gate_t) @ w_out   (fused, f32 ch-major)
    conv2_fused_kernel<<<dim3(NPX / 128), blk, 0, stream>>>(
        att_t, gate_t, w_pre_b, w_out_b, out);
}